// Round 6
// baseline (4414.891 us; speedup 1.0000x reference)
//
#include <hip/hip_runtime.h>

typedef _Float16 half8 __attribute__((ext_vector_type(8)));
typedef float float4v __attribute__((ext_vector_type(4)));

// ---------------------------------------------------------------- small ops

__global__ void pool2_kernel(const float* __restrict__ in, float* __restrict__ out) {
    // [64][96][96] -> [64][48][48], 2x2 mean
    int i = blockIdx.x * 256 + threadIdx.x;
    if (i >= 64 * 48 * 48) return;
    int c = i / 2304, r = i % 2304, ph = r / 48, pw = r % 48;
    const float* p = in + c * 9216 + ph * 2 * 96 + pw * 2;
    out[i] = 0.25f * (p[0] + p[1] + p[96] + p[97]);
}

// fused conv1x1+prelu for embed (64 ch, Wa) and match (32 ch, W1); x read once per
// co-chunk. grid (36, 6): chunks 0-3 -> embed co 0..63, chunks 4-5 -> match co 0..31.
__global__ __launch_bounds__(256) void conv_embed_match(
    const float* __restrict__ x, const float* __restrict__ Wa, const float* __restrict__ ba,
    const float* __restrict__ aa, const float* __restrict__ W1, const float* __restrict__ b1,
    const float* __restrict__ a1, float* __restrict__ embed, float* __restrict__ match) {
    int p = blockIdx.x * 256 + threadIdx.x;  // 9216 pixels
    int chunk = blockIdx.y;
    float xin[64];
#pragma unroll
    for (int ci = 0; ci < 64; ++ci) xin[ci] = x[ci * 9216 + p];
    bool isE = chunk < 4;
    int co0 = (isE ? chunk : chunk - 4) * 16;
    const float* W = isE ? Wa : W1;
    const float* bb = isE ? ba : b1;
    float alpha = (isE ? aa : a1)[0];
    float* dst = isE ? embed : match;
#pragma unroll
    for (int c = 0; c < 16; ++c) {
        int co = co0 + c;
        float s = bb[co];
#pragma unroll
        for (int ci = 0; ci < 64; ++ci) s += W[co * 64 + ci] * xin[ci];
        dst[co * 9216 + p] = s >= 0.f ? s : alpha * s;
    }
}

// co-tiled conv1x1+prelu (CIN=64), 16 outputs per block-row. grid (npix/256, Cout/16)
__global__ __launch_bounds__(256) void conv1x1_tile(const float* __restrict__ in,
                                                    const float* __restrict__ W,
                                                    const float* __restrict__ bias,
                                                    const float* __restrict__ a,
                                                    float* __restrict__ out, int npix) {
    int p = blockIdx.x * 256 + threadIdx.x;
    if (p >= npix) return;
    int co0 = blockIdx.y * 16;
    float xin[64];
#pragma unroll
    for (int ci = 0; ci < 64; ++ci) xin[ci] = in[ci * npix + p];
    float alpha = a[0];
#pragma unroll
    for (int c = 0; c < 16; ++c) {
        int co = co0 + c;
        float s = bias[co];
#pragma unroll
        for (int ci = 0; ci < 64; ++ci) s += W[co * 64 + ci] * xin[ci];
        out[co * npix + p] = s >= 0.f ? s : alpha * s;
    }
}

// xp[q][k=c*9+kh*3+kw] = match[c][qh+kh-1][qw+kw-1] (zero pad), fp16.
// wave per q, lane-contiguous k -> coalesced short stores. grid 2304 x 256.
__global__ __launch_bounds__(256) void build_xp(const float* __restrict__ match,
                                                _Float16* __restrict__ xp) {
    int q = blockIdx.x * 4 + (threadIdx.x >> 6);
    int lane = threadIdx.x & 63;
    int qh = q / 96, qw = q % 96;
#pragma unroll
    for (int t = 0; t < 5; ++t) {
        int k = lane + t * 64;
        if (k < 288) {
            int c = k / 9, r = k % 9;
            int y = qh + r / 3 - 1, x = qw + r % 3 - 1;
            float v = (y >= 0 && y < 96 && x >= 0 && x < 96) ? match[c * 9216 + y * 96 + x] : 0.f;
            xp[(size_t)q * 288 + k] = (_Float16)v;
        }
    }
}

// wn[l][c*9+kh*3+kw] = 10 * patch / max(||patch||, 1e-4), fp16.  1 wave per l.
__global__ void build_wn(const float* __restrict__ ref, _Float16* __restrict__ wn) {
    int l = blockIdx.x;  // 2304
    int oh = l / 48, ow = l % 48;
    int lane = threadIdx.x;  // 64
    float vals[5];
    float ss = 0.f;
#pragma unroll
    for (int t = 0; t < 5; ++t) {
        int i = lane + t * 64;
        float v = 0.f;
        if (i < 288) {
            int c = i / 9, r = i % 9, kh = r / 3, kw = r % 3;
            int y = oh + kh - 1, x = ow + kw - 1;
            v = (y >= 0 && y < 48 && x >= 0 && x < 48) ? ref[c * 2304 + y * 48 + x] : 0.f;
        }
        vals[t] = v;
        ss += v * v;
    }
#pragma unroll
    for (int d = 32; d; d >>= 1) ss += __shfl_xor(ss, d);
    float norm = sqrtf(ss);
    norm = norm < 1e-4f ? 1e-4f : norm;
    float inv = 10.f / norm;  // fold SOFTMAX_SCALE here
#pragma unroll
    for (int t = 0; t < 5; ++t) {
        int i = lane + t * 64;
        if (i < 288) wn[(size_t)l * 288 + i] = (_Float16)(vals[t] * inv);
    }
}

// Wt[row=(o*36+i*6+j)][l=(lh*48+lw)] = embed[o][2lh+i-2][2lw+j-2] (zero pad), fp16
__global__ void build_Wt(const float* __restrict__ embed, _Float16* __restrict__ Wt) {
    int idx = blockIdx.x * 256 + threadIdx.x;
    if (idx >= 2304 * 2304) return;
    int row = idx / 2304, l = idx % 2304;
    int o = row / 36, rem = row % 36, i = rem / 6, j = rem % 6;
    int lh = l / 48, lw = l % 48;
    int y = 2 * lh + i - 2, x = 2 * lw + j - 2;
    float v = (y >= 0 && y < 96 && x >= 0 && x < 96) ? embed[o * 9216 + y * 96 + x] : 0.f;
    Wt[idx] = (_Float16)v;
}

// row softmax over l=2304 per q, writes fp16 normalized weights
__global__ __launch_bounds__(256) void softmax_rows(const float* __restrict__ S,
                                                    _Float16* __restrict__ yi) {
    int q = blockIdx.x;
    const float* row = S + (size_t)q * 2304;
    int tid = threadIdx.x;
    float v[9];
    float m = -1e30f;
#pragma unroll
    for (int t = 0; t < 9; ++t) {
        v[t] = row[tid + t * 256];
        m = fmaxf(m, v[t]);
    }
    __shared__ float red[8];
#pragma unroll
    for (int d = 32; d; d >>= 1) m = fmaxf(m, __shfl_xor(m, d));
    if ((tid & 63) == 0) red[tid >> 6] = m;
    __syncthreads();
    m = fmaxf(fmaxf(red[0], red[1]), fmaxf(red[2], red[3]));
    float s = 0.f;
#pragma unroll
    for (int t = 0; t < 9; ++t) {
        v[t] = expf(v[t] - m);
        s += v[t];
    }
#pragma unroll
    for (int d = 32; d; d >>= 1) s += __shfl_xor(s, d);
    __syncthreads();
    if ((tid & 63) == 0) red[(tid >> 6) + 4] = s;
    __syncthreads();
    s = red[4] + red[5] + red[6] + red[7];
    float inv = 1.f / s;
    _Float16* orow = yi + (size_t)q * 2304;
#pragma unroll
    for (int t = 0; t < 9; ++t) orow[tid + t * 256] = (_Float16)(v[t] * inv);
}

// ---------------------------------------------------------------- MFMA GEMM
// C[M][N] = sum_k A[M][K] * B[N][K]  (K-contiguous fp16), fp32 accum.
// MODE 0: fp32 store.  MODE 1: fp16 store.
// Staging: global_load_lds width-16. Tile = 128 rows x 32 halves = 8 x 1KB chunks
// per matrix; each wave issues 2 A-chunks + 2 B-chunks (c = wave*2 + r, r<2).
// XOR swizzle slot = cc ^ ((row>>1)&3) keeps ds_read_b128 at 2-way/bank (free).
template <int MODE>
__global__ __launch_bounds__(256) void gemm16(const _Float16* __restrict__ A,
                                              const _Float16* __restrict__ B, int M, int N, int K,
                                              void* __restrict__ outv) {
    __shared__ _Float16 As[128 * 32];
    __shared__ _Float16 Bs[128 * 32];
    int tid = threadIdx.x;
    int wave = tid >> 6, lane = tid & 63;
    int wm = wave >> 1, wn_ = wave & 1;  // 2x2 wave grid, 64x64 per wave
    int quad = lane >> 4, mrow = lane & 15;
    int m0 = blockIdx.y * 128, n0 = blockIdx.x * 128;
    int lrow = lane >> 2, lslot = lane & 3;
    float4v acc[4][4] = {};

    for (int k0 = 0; k0 < K; k0 += 32) {
        // chunk c = rows [c*16, c*16+16); lane writes LDS at chunk_base + lane*16B
        // (hardware layout), so source element = (row = c*16 + lane/4,
        //  cc = (lane&3) ^ ((row>>1)&3)) — the inverse of the read swizzle.
#pragma unroll
        for (int r = 0; r < 2; ++r) {
            int c = wave * 2 + r;  // 0..7 — exactly 8 chunks per matrix
            int row = c * 16 + lrow;
            int cc = lslot ^ ((row >> 1) & 3);
            const _Float16* ga = A + (size_t)(m0 + row) * K + k0 + cc * 8;
            const _Float16* gb = B + (size_t)(n0 + row) * K + k0 + cc * 8;
            __builtin_amdgcn_global_load_lds(
                (const __attribute__((address_space(1))) unsigned int*)ga,
                (__attribute__((address_space(3))) unsigned int*)&As[c * 512], 16, 0, 0);
            __builtin_amdgcn_global_load_lds(
                (const __attribute__((address_space(1))) unsigned int*)gb,
                (__attribute__((address_space(3))) unsigned int*)&Bs[c * 512], 16, 0, 0);
        }
        __syncthreads();
        half8 af[4], bf[4];
#pragma unroll
        for (int t = 0; t < 4; ++t) {
            int arow = wm * 64 + t * 16 + mrow;
            af[t] = *(const half8*)&As[arow * 32 + (quad ^ ((arow >> 1) & 3)) * 8];
            int brow = wn_ * 64 + t * 16 + mrow;
            bf[t] = *(const half8*)&Bs[brow * 32 + (quad ^ ((brow >> 1) & 3)) * 8];
        }
#pragma unroll
        for (int i = 0; i < 4; ++i)
#pragma unroll
            for (int j = 0; j < 4; ++j)
                acc[i][j] = __builtin_amdgcn_mfma_f32_16x16x32_f16(af[i], bf[j], acc[i][j], 0, 0, 0);
        __syncthreads();
    }

    // epilogue: D row m = quad*4+r (M dim), col n = lane&15 (N dim)
#pragma unroll
    for (int i = 0; i < 4; ++i)
#pragma unroll
        for (int j = 0; j < 4; ++j)
#pragma unroll
            for (int r = 0; r < 4; ++r) {
                int row = m0 + wm * 64 + i * 16 + quad * 4 + r;
                int col = n0 + wn_ * 64 + j * 16 + mrow;
                float v = acc[i][j][r];
                if (MODE == 0) {
                    ((float*)outv)[(size_t)row * N + col] = v;
                } else {
                    ((_Float16*)outv)[(size_t)row * N + col] = (_Float16)v;
                }
            }
}

// ---------------------------------------------------------------- composed tail
// CW[t=(th*4+tw)][op][l] = sum_o sum_{(dy,i): i=dy+5-2th} sum_{(dx,j): j=dx+5-2tw}
//                          Wd[op][(o,dy,dx)] * Wt[(o,i,j)][l]
// CWe groups: 0..3 row-corr (dy=0,i=1 fixed; tw = group), 4..7 col-corr
// (dx=0,j=1 fixed; th = group-4), 8 corner (dy=0,i=1,dx=0,j=1).
// grid (9, 25), block 256: thread = one l, accumulates all 64 op (Wd loads are
// wave-uniform -> scalar broadcast).
__global__ void cw_build(const float* __restrict__ Wd, const _Float16* __restrict__ Wt,
                         _Float16* __restrict__ CW, _Float16* __restrict__ CWe) {
    int l = blockIdx.x * 256 + threadIdx.x;  // 0..2303
    int t = blockIdx.y;                      // 0..24
    float acc[64];
#pragma unroll
    for (int op = 0; op < 64; ++op) acc[op] = 0.f;

    int dylist[3], ilist[3], ndy = 0;
    int dxlist[3], jlist[3], ndx = 0;
    if (t < 16 || (t >= 20 && t < 24)) {
        int th = (t < 16) ? (t >> 2) : (t - 20);
        for (int dy = 0; dy < 3; ++dy) {
            int i = dy + 5 - 2 * th;
            if (i >= 0 && i < 6) { dylist[ndy] = dy; ilist[ndy] = i; ++ndy; }
        }
    } else {  // row-corr or corner: dy=0, i=1
        dylist[0] = 0; ilist[0] = 1; ndy = 1;
    }
    if (t < 16 || (t >= 16 && t < 20)) {
        int tw = (t < 16) ? (t & 3) : (t - 16);
        for (int dx = 0; dx < 3; ++dx) {
            int j = dx + 5 - 2 * tw;
            if (j >= 0 && j < 6) { dxlist[ndx] = dx; jlist[ndx] = j; ++ndx; }
        }
    } else {  // col-corr or corner: dx=0, j=1
        dxlist[0] = 0; jlist[0] = 1; ndx = 1;
    }

    for (int o = 0; o < 64; ++o)
        for (int a = 0; a < ndy; ++a)
            for (int b = 0; b < ndx; ++b) {
                float wt = (float)Wt[(size_t)(o * 36 + ilist[a] * 6 + jlist[b]) * 2304 + l];
                const float* wd = Wd + o * 9 + dylist[a] * 3 + dxlist[b];
#pragma unroll
                for (int op = 0; op < 64; ++op) acc[op] += wd[op * 576] * wt;
            }

    _Float16* dst = (t < 16) ? (CW + (size_t)t * 64 * 2304 + l)
                             : (CWe + (size_t)(t - 16) * 64 * 2304 + l);
#pragma unroll
    for (int op = 0; op < 64; ++op) dst[(size_t)op * 2304] = (_Float16)acc[op];
}

// boundary corrections. grid 193: blk 0..95 -> corrROW[.][x=blk], 96..191 ->
// corrCOL[.][y=blk-96], 192 -> corner. Each block: <=4 (group, yi-row) pairs,
// 64-op dot-products over l=2304 (yi rows staged in LDS).
__global__ __launch_bounds__(256) void corr_kernel(const _Float16* __restrict__ CWe,
                                                   const _Float16* __restrict__ yi,
                                                   float* __restrict__ corrROW,
                                                   float* __restrict__ corrCOL,
                                                   float* __restrict__ corner) {
    int blk = blockIdx.x;
    int tid = threadIdx.x, lane = tid & 63, w = tid >> 6;
    __shared__ _Float16 yrow[4][2304];
    __shared__ int groups[4];
    __shared__ int npairs_s;

    if (tid == 0) {
        int np = 0;
        if (blk < 96) {
            int x = blk;
            for (int tw = 0; tw < 4; ++tw) {
                int xw = x + tw - 2;
                if (xw >= 0 && xw < 96) groups[np++] = tw;  // q' = xw
            }
        } else if (blk < 192) {
            int y = blk - 96;
            for (int th = 0; th < 4; ++th) {
                int yh = y + th - 2;
                if (yh >= 0 && yh < 96) groups[np++] = 4 + th;  // q' = yh*96
            }
        } else {
            groups[np++] = 8;  // q' = 0
        }
        npairs_s = np;
    }
    __syncthreads();
    int np = npairs_s;
    // stage yi rows
    for (int p = 0; p < np; ++p) {
        int g = groups[p], qp;
        if (blk < 96) qp = blk + (g - 0) - 2;          // row: q' = x+tw-2
        else if (blk < 192) qp = ((blk - 96) + (g - 4) - 2) * 96;
        else qp = 0;
        for (int l = tid; l < 2304; l += 256) yrow[p][l] = yi[(size_t)qp * 2304 + l];
    }
    __syncthreads();

    for (int gi = 0; gi < 16; ++gi) {
        int op = gi * 4 + w;
        float s = 0.f;
        for (int p = 0; p < np; ++p) {
            const _Float16* cwe = CWe + ((size_t)groups[p] * 64 + op) * 2304;
            for (int l = lane; l < 2304; l += 64) s += (float)cwe[l] * (float)yrow[p][l];
        }
#pragma unroll
        for (int d = 32; d; d >>= 1) s += __shfl_xor(s, d);
        if (lane == 0) {
            if (blk < 96) corrROW[op * 96 + blk] = s;
            else if (blk < 192) corrCOL[op * 96 + (blk - 96)] = s;
            else corner[op] = s;
        }
    }
}

// out[op][y][x] = (bd[op] + sum_taps Z2[(t*64+op)][(y+th-2)*96+(x+tw-2)]
//                 - row/col corrections + corner) / 6
__global__ __launch_bounds__(256) void combine_kernel(
    const _Float16* __restrict__ Z2, const float* __restrict__ corrROW,
    const float* __restrict__ corrCOL, const float* __restrict__ corner,
    const float* __restrict__ bd, float* __restrict__ out) {
    int idx = blockIdx.x * 256 + threadIdx.x;
    if (idx >= 64 * 9216) return;
    int op = idx / 9216, q = idx % 9216, y = q / 96, x = q % 96;
    float s = 0.f;
#pragma unroll
    for (int th = 0; th < 4; ++th)
#pragma unroll
        for (int tw = 0; tw < 4; ++tw) {
            int yy = y + th - 2, xx = x + tw - 2;
            if (yy >= 0 && yy < 96 && xx >= 0 && xx < 96)
                s += (float)Z2[(size_t)((th * 4 + tw) * 64 + op) * 9216 + yy * 96 + xx];
        }
    if (y == 0) s -= corrROW[op * 96 + x];
    if (x == 0) s -= corrCOL[op * 96 + y];
    if (y == 0 && x == 0) s += corner[op];
    out[idx] = (s + bd[op]) * (1.f / 6.f);
}

// ---------------------------------------------------------------- launch

extern "C" void kernel_launch(void* const* d_in, const int* in_sizes, int n_in,
                              void* d_out, int out_size, void* d_ws, size_t ws_size,
                              hipStream_t stream) {
    const float* x = (const float*)d_in[0];
    const float* W1 = (const float*)d_in[1];
    const float* b1 = (const float*)d_in[2];
    const float* a1 = (const float*)d_in[3];
    const float* W2 = (const float*)d_in[4];
    const float* b2 = (const float*)d_in[5];
    const float* a2 = (const float*)d_in[6];
    const float* Wa = (const float*)d_in[7];
    const float* ba = (const float*)d_in[8];
    const float* aa = (const float*)d_in[9];
    const float* Wd = (const float*)d_in[10];
    const float* bd = (const float*)d_in[11];
    float* out = (float*)d_out;

    char* ws = (char*)d_ws;
    float* S = (float*)ws;          ws += 84934656;   // [9216][2304] fp32 logits (dead after softmax)
    _Float16* yi = (_Float16*)ws;   ws += 42467328;   // [9216][2304] fp16 softmax
    _Float16* Wt = (_Float16*)ws;   ws += 10616832;   // [2304][2304] fp16 raw_w^T
    _Float16* xp = (_Float16*)ws;   ws += 5308416;    // [9216][288] fp16
    _Float16* wn = (_Float16*)ws;   ws += 1327104;    // [2304][288] fp16 (x10 folded)
    float* embed = (float*)ws;      ws += 2359296;    // [64][96][96]
    float* match = (float*)ws;      ws += 1179648;    // [32][96][96]
    float* pooled = (float*)ws;     ws += 589824;     // [64][48][48]
    float* refb = (float*)ws;       ws += 294912;     // [32][48][48]
    // aliases into the dead-after-softmax S region (all writers run after softmax):
    char* sreg = (char*)S;
    _Float16* Z2 = (_Float16*)sreg;                    // [1024][9216] fp16 = 18,874,368 B
    _Float16* CW = (_Float16*)(sreg + 18874368);       // [16][64][2304] fp16 = 4,718,592 B
    _Float16* CWe = (_Float16*)(sreg + 23592960);      // [9][64][2304] fp16 = 2,654,208 B
    float* corrROW = (float*)(sreg + 26247168);        // [64][96] f32
    float* corrCOL = (float*)(sreg + 26271744);        // [64][96] f32
    float* corner = (float*)(sreg + 26296320);         // [64] f32

    for (int b = 0; b < 2; ++b) {
        const float* xb = x + (size_t)b * 64 * 9216;
        float* outb = out + (size_t)b * 64 * 9216;

        pool2_kernel<<<576, 256, 0, stream>>>(xb, pooled);
        conv_embed_match<<<dim3(36, 6), 256, 0, stream>>>(xb, Wa, ba, aa, W1, b1, a1, embed, match);
        conv1x1_tile<<<dim3(9, 2), 256, 0, stream>>>(pooled, W2, b2, a2, refb, 2304);
        build_xp<<<2304, 256, 0, stream>>>(match, xp);
        build_wn<<<2304, 64, 0, stream>>>(refb, wn);
        build_Wt<<<20736, 256, 0, stream>>>(embed, Wt);

        // GEMM1: S[q][l] = <xp[q], wn[l]> (x10 folded into wn)
        gemm16<0><<<dim3(18, 72), 256, 0, stream>>>(xp, wn, 9216, 2304, 288, S);
        softmax_rows<<<9216, 256, 0, stream>>>(S, yi);

        // composed down-conv weights (S is dead now; CW/CWe live in its region)
        cw_build<<<dim3(9, 25), 256, 0, stream>>>(Wd, Wt, CW, CWe);

        // main GEMM: Z2[(t*64+op)][q] = sum_l CW[t][op][l] * yi[q][l]
        gemm16<1><<<dim3(72, 8), 256, 0, stream>>>(CW, yi, 1024, 9216, 2304, Z2);

        corr_kernel<<<193, 256, 0, stream>>>(CWe, yi, corrROW, corrCOL, corner);
        combine_kernel<<<2304, 256, 0, stream>>>(Z2, corrROW, corrCOL, corner, bd, outb);
    }
}

// Round 7
// 2821.225 us; speedup vs baseline: 1.5649x; 1.5649x over previous
//
#include <hip/hip_runtime.h>

typedef _Float16 half8 __attribute__((ext_vector_type(8)));
typedef float float4v __attribute__((ext_vector_type(4)));

// ---------------------------------------------------------------- small ops

__global__ void pool2_kernel(const float* __restrict__ in, float* __restrict__ out) {
    // [64][96][96] -> [64][48][48], 2x2 mean
    int i = blockIdx.x * 256 + threadIdx.x;
    if (i >= 64 * 48 * 48) return;
    int c = i / 2304, r = i % 2304, ph = r / 48, pw = r % 48;
    const float* p = in + c * 9216 + ph * 2 * 96 + pw * 2;
    out[i] = 0.25f * (p[0] + p[1] + p[96] + p[97]);
}

// fused conv1x1+prelu for embed (64 ch, Wa) and match (32 ch, W1); x read once per
// co-chunk. grid (36, 6): chunks 0-3 -> embed co 0..63, chunks 4-5 -> match co 0..31.
__global__ __launch_bounds__(256) void conv_embed_match(
    const float* __restrict__ x, const float* __restrict__ Wa, const float* __restrict__ ba,
    const float* __restrict__ aa, const float* __restrict__ W1, const float* __restrict__ b1,
    const float* __restrict__ a1, float* __restrict__ embed, float* __restrict__ match) {
    int p = blockIdx.x * 256 + threadIdx.x;  // 9216 pixels
    int chunk = blockIdx.y;
    float xin[64];
#pragma unroll
    for (int ci = 0; ci < 64; ++ci) xin[ci] = x[ci * 9216 + p];
    bool isE = chunk < 4;
    int co0 = (isE ? chunk : chunk - 4) * 16;
    const float* W = isE ? Wa : W1;
    const float* bb = isE ? ba : b1;
    float alpha = (isE ? aa : a1)[0];
    float* dst = isE ? embed : match;
#pragma unroll
    for (int c = 0; c < 16; ++c) {
        int co = co0 + c;
        float s = bb[co];
#pragma unroll
        for (int ci = 0; ci < 64; ++ci) s += W[co * 64 + ci] * xin[ci];
        dst[co * 9216 + p] = s >= 0.f ? s : alpha * s;
    }
}

// co-tiled conv1x1+prelu (CIN=64), 16 outputs per block-row. grid (npix/256, Cout/16)
__global__ __launch_bounds__(256) void conv1x1_tile(const float* __restrict__ in,
                                                    const float* __restrict__ W,
                                                    const float* __restrict__ bias,
                                                    const float* __restrict__ a,
                                                    float* __restrict__ out, int npix) {
    int p = blockIdx.x * 256 + threadIdx.x;
    if (p >= npix) return;
    int co0 = blockIdx.y * 16;
    float xin[64];
#pragma unroll
    for (int ci = 0; ci < 64; ++ci) xin[ci] = in[ci * npix + p];
    float alpha = a[0];
#pragma unroll
    for (int c = 0; c < 16; ++c) {
        int co = co0 + c;
        float s = bias[co];
#pragma unroll
        for (int ci = 0; ci < 64; ++ci) s += W[co * 64 + ci] * xin[ci];
        out[co * npix + p] = s >= 0.f ? s : alpha * s;
    }
}

// xp[q][k=c*9+kh*3+kw] = match[c][qh+kh-1][qw+kw-1] (zero pad), fp16.
// wave per q, lane-contiguous k -> coalesced short stores. grid 2304 x 256.
__global__ __launch_bounds__(256) void build_xp(const float* __restrict__ match,
                                                _Float16* __restrict__ xp) {
    int q = blockIdx.x * 4 + (threadIdx.x >> 6);
    int lane = threadIdx.x & 63;
    int qh = q / 96, qw = q % 96;
#pragma unroll
    for (int t = 0; t < 5; ++t) {
        int k = lane + t * 64;
        if (k < 288) {
            int c = k / 9, r = k % 9;
            int y = qh + r / 3 - 1, x = qw + r % 3 - 1;
            float v = (y >= 0 && y < 96 && x >= 0 && x < 96) ? match[c * 9216 + y * 96 + x] : 0.f;
            xp[(size_t)q * 288 + k] = (_Float16)v;
        }
    }
}

// wn[l][c*9+kh*3+kw] = 10 * patch / max(||patch||, 1e-4), fp16.  1 wave per l.
__global__ void build_wn(const float* __restrict__ ref, _Float16* __restrict__ wn) {
    int l = blockIdx.x;  // 2304
    int oh = l / 48, ow = l % 48;
    int lane = threadIdx.x;  // 64
    float vals[5];
    float ss = 0.f;
#pragma unroll
    for (int t = 0; t < 5; ++t) {
        int i = lane + t * 64;
        float v = 0.f;
        if (i < 288) {
            int c = i / 9, r = i % 9, kh = r / 3, kw = r % 3;
            int y = oh + kh - 1, x = ow + kw - 1;
            v = (y >= 0 && y < 48 && x >= 0 && x < 48) ? ref[c * 2304 + y * 48 + x] : 0.f;
        }
        vals[t] = v;
        ss += v * v;
    }
#pragma unroll
    for (int d = 32; d; d >>= 1) ss += __shfl_xor(ss, d);
    float norm = sqrtf(ss);
    norm = norm < 1e-4f ? 1e-4f : norm;
    float inv = 10.f / norm;  // fold SOFTMAX_SCALE here
#pragma unroll
    for (int t = 0; t < 5; ++t) {
        int i = lane + t * 64;
        if (i < 288) wn[(size_t)l * 288 + i] = (_Float16)(vals[t] * inv);
    }
}

// Wt[row=(o*36+i*6+j)][l=(lh*48+lw)] = embed[o][2lh+i-2][2lw+j-2] (zero pad), fp16
__global__ void build_Wt(const float* __restrict__ embed, _Float16* __restrict__ Wt) {
    int idx = blockIdx.x * 256 + threadIdx.x;
    if (idx >= 2304 * 2304) return;
    int row = idx / 2304, l = idx % 2304;
    int o = row / 36, rem = row % 36, i = rem / 6, j = rem % 6;
    int lh = l / 48, lw = l % 48;
    int y = 2 * lh + i - 2, x = 2 * lw + j - 2;
    float v = (y >= 0 && y < 96 && x >= 0 && x < 96) ? embed[o * 9216 + y * 96 + x] : 0.f;
    Wt[idx] = (_Float16)v;
}

// row softmax over l=2304 per q, writes fp16 normalized weights
__global__ __launch_bounds__(256) void softmax_rows(const float* __restrict__ S,
                                                    _Float16* __restrict__ yi) {
    int q = blockIdx.x;
    const float* row = S + (size_t)q * 2304;
    int tid = threadIdx.x;
    float v[9];
    float m = -1e30f;
#pragma unroll
    for (int t = 0; t < 9; ++t) {
        v[t] = row[tid + t * 256];
        m = fmaxf(m, v[t]);
    }
    __shared__ float red[8];
#pragma unroll
    for (int d = 32; d; d >>= 1) m = fmaxf(m, __shfl_xor(m, d));
    if ((tid & 63) == 0) red[tid >> 6] = m;
    __syncthreads();
    m = fmaxf(fmaxf(red[0], red[1]), fmaxf(red[2], red[3]));
    float s = 0.f;
#pragma unroll
    for (int t = 0; t < 9; ++t) {
        v[t] = expf(v[t] - m);
        s += v[t];
    }
#pragma unroll
    for (int d = 32; d; d >>= 1) s += __shfl_xor(s, d);
    __syncthreads();
    if ((tid & 63) == 0) red[(tid >> 6) + 4] = s;
    __syncthreads();
    s = red[4] + red[5] + red[6] + red[7];
    float inv = 1.f / s;
    _Float16* orow = yi + (size_t)q * 2304;
#pragma unroll
    for (int t = 0; t < 9; ++t) orow[tid + t * 256] = (_Float16)(v[t] * inv);
}

// ---------------------------------------------------------------- MFMA GEMM
// C[M][N] = sum_k A[M][K] * B[N][K]  (K-contiguous fp16), fp32 accum.
// MODE 0: fp32 store.  MODE 1: fp16 store.
// Staging: global_load_lds width-16. Tile = 128 rows x 32 halves = 8 x 1KB chunks
// per matrix; each wave issues 2 A-chunks + 2 B-chunks (c = wave*2 + r, r<2).
// XOR swizzle slot = cc ^ ((row>>1)&3) keeps ds_read_b128 at 2-way/bank (free).
template <int MODE>
__global__ __launch_bounds__(256) void gemm16(const _Float16* __restrict__ A,
                                              const _Float16* __restrict__ B, int M, int N, int K,
                                              void* __restrict__ outv) {
    __shared__ _Float16 As[128 * 32];
    __shared__ _Float16 Bs[128 * 32];
    int tid = threadIdx.x;
    int wave = tid >> 6, lane = tid & 63;
    int wm = wave >> 1, wn_ = wave & 1;  // 2x2 wave grid, 64x64 per wave
    int quad = lane >> 4, mrow = lane & 15;
    int m0 = blockIdx.y * 128, n0 = blockIdx.x * 128;
    int lrow = lane >> 2, lslot = lane & 3;
    float4v acc[4][4] = {};

    for (int k0 = 0; k0 < K; k0 += 32) {
        // chunk c = rows [c*16, c*16+16); lane writes LDS at chunk_base + lane*16B
        // (hardware layout), so source element = (row = c*16 + lane/4,
        //  cc = (lane&3) ^ ((row>>1)&3)) — the inverse of the read swizzle.
#pragma unroll
        for (int r = 0; r < 2; ++r) {
            int c = wave * 2 + r;  // 0..7 — exactly 8 chunks per matrix
            int row = c * 16 + lrow;
            int cc = lslot ^ ((row >> 1) & 3);
            const _Float16* ga = A + (size_t)(m0 + row) * K + k0 + cc * 8;
            const _Float16* gb = B + (size_t)(n0 + row) * K + k0 + cc * 8;
            __builtin_amdgcn_global_load_lds(
                (const __attribute__((address_space(1))) unsigned int*)ga,
                (__attribute__((address_space(3))) unsigned int*)&As[c * 512], 16, 0, 0);
            __builtin_amdgcn_global_load_lds(
                (const __attribute__((address_space(1))) unsigned int*)gb,
                (__attribute__((address_space(3))) unsigned int*)&Bs[c * 512], 16, 0, 0);
        }
        __syncthreads();
        half8 af[4], bf[4];
#pragma unroll
        for (int t = 0; t < 4; ++t) {
            int arow = wm * 64 + t * 16 + mrow;
            af[t] = *(const half8*)&As[arow * 32 + (quad ^ ((arow >> 1) & 3)) * 8];
            int brow = wn_ * 64 + t * 16 + mrow;
            bf[t] = *(const half8*)&Bs[brow * 32 + (quad ^ ((brow >> 1) & 3)) * 8];
        }
#pragma unroll
        for (int i = 0; i < 4; ++i)
#pragma unroll
            for (int j = 0; j < 4; ++j)
                acc[i][j] = __builtin_amdgcn_mfma_f32_16x16x32_f16(af[i], bf[j], acc[i][j], 0, 0, 0);
        __syncthreads();
    }

    // epilogue: D row m = quad*4+r (M dim), col n = lane&15 (N dim)
#pragma unroll
    for (int i = 0; i < 4; ++i)
#pragma unroll
        for (int j = 0; j < 4; ++j)
#pragma unroll
            for (int r = 0; r < 4; ++r) {
                int row = m0 + wm * 64 + i * 16 + quad * 4 + r;
                int col = n0 + wn_ * 64 + j * 16 + mrow;
                float v = acc[i][j][r];
                if (MODE == 0) {
                    ((float*)outv)[(size_t)row * N + col] = v;
                } else {
                    ((_Float16*)outv)[(size_t)row * N + col] = (_Float16)v;
                }
            }
}

// ---------------------------------------------------------------- composed tail
// CW[t=(th*4+tw)][op][l] = sum_o sum_{(dy,i): i=dy+5-2th} sum_{(dx,j): j=dx+5-2tw}
//                          Wd[op][(o,dy,dx)] * Wt[(o,i,j)][l]
// CWe groups: 0..3 row-corr (dy=0,i=1 fixed; tw = group), 4..7 col-corr
// (dx=0,j=1 fixed; th = group-4), 8 corner (dy=0,i=1,dx=0,j=1).
// One SCALAR accumulator per thread (the round-6 acc[64] version spilled to
// scratch: VGPR=44 < 64 floats -> 1.4 ms). op is wave-uniform -> Wd s_loads;
// l is lane-contiguous -> coalesced Wt reads. grid (36 l, 16 op, 25 t).
__global__ __launch_bounds__(256) void cw_build(const float* __restrict__ Wd,
                                                const _Float16* __restrict__ Wt,
                                                _Float16* __restrict__ CW,
                                                _Float16* __restrict__ CWe) {
    int lane = threadIdx.x & 63, w = threadIdx.x >> 6;
    int l = blockIdx.x * 64 + lane;
    int op = blockIdx.y * 4 + w;
    int t = blockIdx.z;

    int dylist[3], ilist[3], ndy = 0;
    int dxlist[3], jlist[3], ndx = 0;
    if (t < 16 || (t >= 20 && t < 24)) {
        int th = (t < 16) ? (t >> 2) : (t - 20);
        for (int dy = 0; dy < 3; ++dy) {
            int i = dy + 5 - 2 * th;
            if (i >= 0 && i < 6) { dylist[ndy] = dy; ilist[ndy] = i; ++ndy; }
        }
    } else {  // row-corr or corner: dy=0, i=1
        dylist[0] = 0; ilist[0] = 1; ndy = 1;
    }
    if (t < 20) {
        int tw = (t < 16) ? (t & 3) : (t - 16);
        for (int dx = 0; dx < 3; ++dx) {
            int j = dx + 5 - 2 * tw;
            if (j >= 0 && j < 6) { dxlist[ndx] = dx; jlist[ndx] = j; ++ndx; }
        }
    } else {  // col-corr or corner: dx=0, j=1
        dxlist[0] = 0; jlist[0] = 1; ndx = 1;
    }

    float acc = 0.f;
    const float* wdrow = Wd + op * 576;
    for (int o = 0; o < 64; ++o)
        for (int a = 0; a < ndy; ++a)
            for (int b = 0; b < ndx; ++b)
                acc += wdrow[o * 9 + dylist[a] * 3 + dxlist[b]] *
                       (float)Wt[(size_t)(o * 36 + ilist[a] * 6 + jlist[b]) * 2304 + l];

    if (t < 16) CW[((size_t)t * 64 + op) * 2304 + l] = (_Float16)acc;
    else        CWe[((size_t)(t - 16) * 64 + op) * 2304 + l] = (_Float16)acc;
}

// boundary corrections. grid 193: blk 0..95 -> corrROW[.][x=blk], 96..191 ->
// corrCOL[.][y=blk-96], 192 -> corner. Each block: <=4 (group, yi-row) pairs,
// 64-op dot-products over l=2304 (yi rows staged in LDS).
__global__ __launch_bounds__(256) void corr_kernel(const _Float16* __restrict__ CWe,
                                                   const _Float16* __restrict__ yi,
                                                   float* __restrict__ corrROW,
                                                   float* __restrict__ corrCOL,
                                                   float* __restrict__ corner) {
    int blk = blockIdx.x;
    int tid = threadIdx.x, lane = tid & 63, w = tid >> 6;
    __shared__ _Float16 yrow[4][2304];
    __shared__ int groups[4];
    __shared__ int npairs_s;

    if (tid == 0) {
        int np = 0;
        if (blk < 96) {
            int x = blk;
            for (int tw = 0; tw < 4; ++tw) {
                int xw = x + tw - 2;
                if (xw >= 0 && xw < 96) groups[np++] = tw;  // q' = xw
            }
        } else if (blk < 192) {
            int y = blk - 96;
            for (int th = 0; th < 4; ++th) {
                int yh = y + th - 2;
                if (yh >= 0 && yh < 96) groups[np++] = 4 + th;  // q' = yh*96
            }
        } else {
            groups[np++] = 8;  // q' = 0
        }
        npairs_s = np;
    }
    __syncthreads();
    int np = npairs_s;
    // stage yi rows
    for (int p = 0; p < np; ++p) {
        int g = groups[p], qp;
        if (blk < 96) qp = blk + (g - 0) - 2;          // row: q' = x+tw-2
        else if (blk < 192) qp = ((blk - 96) + (g - 4) - 2) * 96;
        else qp = 0;
        for (int l = tid; l < 2304; l += 256) yrow[p][l] = yi[(size_t)qp * 2304 + l];
    }
    __syncthreads();

    for (int gi = 0; gi < 16; ++gi) {
        int op = gi * 4 + w;
        float s = 0.f;
        for (int p = 0; p < np; ++p) {
            const _Float16* cwe = CWe + ((size_t)groups[p] * 64 + op) * 2304;
            for (int l = lane; l < 2304; l += 64) s += (float)cwe[l] * (float)yrow[p][l];
        }
#pragma unroll
        for (int d = 32; d; d >>= 1) s += __shfl_xor(s, d);
        if (lane == 0) {
            if (blk < 96) corrROW[op * 96 + blk] = s;
            else if (blk < 192) corrCOL[op * 96 + (blk - 96)] = s;
            else corner[op] = s;
        }
    }
}

// out[op][y][x] = (bd[op] + sum_taps Z2[(t*64+op)][(y+th-2)*96+(x+tw-2)]
//                 - row/col corrections + corner) / 6
__global__ __launch_bounds__(256) void combine_kernel(
    const _Float16* __restrict__ Z2, const float* __restrict__ corrROW,
    const float* __restrict__ corrCOL, const float* __restrict__ corner,
    const float* __restrict__ bd, float* __restrict__ out) {
    int idx = blockIdx.x * 256 + threadIdx.x;
    if (idx >= 64 * 9216) return;
    int op = idx / 9216, q = idx % 9216, y = q / 96, x = q % 96;
    float s = 0.f;
#pragma unroll
    for (int th = 0; th < 4; ++th)
#pragma unroll
        for (int tw = 0; tw < 4; ++tw) {
            int yy = y + th - 2, xx = x + tw - 2;
            if (yy >= 0 && yy < 96 && xx >= 0 && xx < 96)
                s += (float)Z2[(size_t)((th * 4 + tw) * 64 + op) * 9216 + yy * 96 + xx];
        }
    if (y == 0) s -= corrROW[op * 96 + x];
    if (x == 0) s -= corrCOL[op * 96 + y];
    if (y == 0 && x == 0) s += corner[op];
    out[idx] = (s + bd[op]) * (1.f / 6.f);
}

// ---------------------------------------------------------------- launch

extern "C" void kernel_launch(void* const* d_in, const int* in_sizes, int n_in,
                              void* d_out, int out_size, void* d_ws, size_t ws_size,
                              hipStream_t stream) {
    const float* x = (const float*)d_in[0];
    const float* W1 = (const float*)d_in[1];
    const float* b1 = (const float*)d_in[2];
    const float* a1 = (const float*)d_in[3];
    const float* W2 = (const float*)d_in[4];
    const float* b2 = (const float*)d_in[5];
    const float* a2 = (const float*)d_in[6];
    const float* Wa = (const float*)d_in[7];
    const float* ba = (const float*)d_in[8];
    const float* aa = (const float*)d_in[9];
    const float* Wd = (const float*)d_in[10];
    const float* bd = (const float*)d_in[11];
    float* out = (float*)d_out;

    char* ws = (char*)d_ws;
    float* S = (float*)ws;          ws += 84934656;   // [9216][2304] fp32 logits (dead after softmax)
    _Float16* yi = (_Float16*)ws;   ws += 42467328;   // [9216][2304] fp16 softmax
    _Float16* Wt = (_Float16*)ws;   ws += 10616832;   // [2304][2304] fp16 raw_w^T
    _Float16* xp = (_Float16*)ws;   ws += 5308416;    // [9216][288] fp16
    _Float16* wn = (_Float16*)ws;   ws += 1327104;    // [2304][288] fp16 (x10 folded)
    float* embed = (float*)ws;      ws += 2359296;    // [64][96][96]
    float* match = (float*)ws;      ws += 1179648;    // [32][96][96]
    float* pooled = (float*)ws;     ws += 589824;     // [64][48][48]
    float* refb = (float*)ws;       ws += 294912;     // [32][48][48]
    // aliases into the dead-after-softmax S region (all writers run after softmax):
    char* sreg = (char*)S;
    _Float16* Z2 = (_Float16*)sreg;                    // [1024][9216] fp16 = 18,874,368 B
    _Float16* CW = (_Float16*)(sreg + 18874368);       // [16][64][2304] fp16 = 4,718,592 B
    _Float16* CWe = (_Float16*)(sreg + 23592960);      // [9][64][2304] fp16 = 2,654,208 B
    float* corrROW = (float*)(sreg + 26247168);        // [64][96] f32
    float* corrCOL = (float*)(sreg + 26271744);        // [64][96] f32
    float* corner = (float*)(sreg + 26296320);         // [64] f32

    for (int b = 0; b < 2; ++b) {
        const float* xb = x + (size_t)b * 64 * 9216;
        float* outb = out + (size_t)b * 64 * 9216;

        pool2_kernel<<<576, 256, 0, stream>>>(xb, pooled);
        conv_embed_match<<<dim3(36, 6), 256, 0, stream>>>(xb, Wa, ba, aa, W1, b1, a1, embed, match);
        conv1x1_tile<<<dim3(9, 2), 256, 0, stream>>>(pooled, W2, b2, a2, refb, 2304);
        build_xp<<<2304, 256, 0, stream>>>(match, xp);
        build_wn<<<2304, 64, 0, stream>>>(refb, wn);
        build_Wt<<<20736, 256, 0, stream>>>(embed, Wt);

        // GEMM1: S[q][l] = <xp[q], wn[l]> (x10 folded into wn)
        gemm16<0><<<dim3(18, 72), 256, 0, stream>>>(xp, wn, 9216, 2304, 288, S);
        softmax_rows<<<9216, 256, 0, stream>>>(S, yi);

        // composed down-conv weights (S is dead now; CW/CWe live in its region)
        cw_build<<<dim3(36, 16, 25), 256, 0, stream>>>(Wd, Wt, CW, CWe);

        // main GEMM: Z2[(t*64+op)][q] = sum_l CW[t][op][l] * yi[q][l]
        gemm16<1><<<dim3(72, 8), 256, 0, stream>>>(CW, yi, 1024, 9216, 2304, Z2);

        corr_kernel<<<193, 256, 0, stream>>>(CWe, yi, corrROW, corrCOL, corner);
        combine_kernel<<<2304, 256, 0, stream>>>(Z2, corrROW, corrCOL, corner, bd, outb);
    }
}

// Round 8
// 638.832 us; speedup vs baseline: 6.9109x; 4.4162x over previous
//
#include <hip/hip_runtime.h>

typedef _Float16 half8 __attribute__((ext_vector_type(8)));
typedef float float4v __attribute__((ext_vector_type(4)));

// ---------------------------------------------------------------- front (batched over z)

// fused conv1x1+prelu for embed (64 ch, Wa) and match (32 ch, W1); x read once per
// co-chunk. grid (36, 6, B): chunks 0-3 -> embed co 0..63, chunks 4-5 -> match co 0..31.
__global__ __launch_bounds__(256) void conv_embed_match(
    const float* __restrict__ x, const float* __restrict__ Wa, const float* __restrict__ ba,
    const float* __restrict__ aa, const float* __restrict__ W1, const float* __restrict__ b1,
    const float* __restrict__ a1, float* __restrict__ embed2, float* __restrict__ match2) {
    int b = blockIdx.z;
    const float* xb = x + (size_t)b * 64 * 9216;
    int p = blockIdx.x * 256 + threadIdx.x;  // 9216 pixels
    int chunk = blockIdx.y;
    float xin[64];
#pragma unroll
    for (int ci = 0; ci < 64; ++ci) xin[ci] = xb[ci * 9216 + p];
    bool isE = chunk < 4;
    int co0 = (isE ? chunk : chunk - 4) * 16;
    const float* W = isE ? Wa : W1;
    const float* bb = isE ? ba : b1;
    float alpha = (isE ? aa : a1)[0];
    float* dst = isE ? (embed2 + (size_t)b * 64 * 9216) : (match2 + (size_t)b * 32 * 9216);
#pragma unroll
    for (int c = 0; c < 16; ++c) {
        int co = co0 + c;
        float s = bb[co];
#pragma unroll
        for (int ci = 0; ci < 64; ++ci) s += W[co * 64 + ci] * xin[ci];
        dst[co * 9216 + p] = s >= 0.f ? s : alpha * s;
    }
}

// ref conv with inline 2x2 mean pool: refb[b][co][ph][pw] = prelu(W2 . pool(x)).
// grid (9, 2, B): 2304 pooled pixels x 16-co chunks.
__global__ __launch_bounds__(256) void conv_ref_pooled(
    const float* __restrict__ x, const float* __restrict__ W2, const float* __restrict__ b2,
    const float* __restrict__ a2, float* __restrict__ refb2) {
    int b = blockIdx.z;
    const float* xb = x + (size_t)b * 64 * 9216;
    int p = blockIdx.x * 256 + threadIdx.x;  // 0..2303
    int ph = p / 48, pw = p % 48;
    int co0 = blockIdx.y * 16;
    float xin[64];
#pragma unroll
    for (int ci = 0; ci < 64; ++ci) {
        const float* q = xb + ci * 9216 + ph * 2 * 96 + pw * 2;
        xin[ci] = 0.25f * (q[0] + q[1] + q[96] + q[97]);
    }
    float alpha = a2[0];
    float* dst = refb2 + (size_t)b * 32 * 2304;
#pragma unroll
    for (int c = 0; c < 16; ++c) {
        int co = co0 + c;
        float s = b2[co];
#pragma unroll
        for (int ci = 0; ci < 64; ++ci) s += W2[co * 64 + ci] * xin[ci];
        dst[co * 2304 + p] = s >= 0.f ? s : alpha * s;
    }
}

// ---------------------------------------------------------------- per-batch builds

// xp[q][k=c*9+kh*3+kw] = match[c][qh+kh-1][qw+kw-1] (zero pad), fp16.
// wave per q, lane-contiguous k -> coalesced short stores. grid 2304 x 256.
__global__ __launch_bounds__(256) void build_xp(const float* __restrict__ match,
                                                _Float16* __restrict__ xp) {
    int q = blockIdx.x * 4 + (threadIdx.x >> 6);
    int lane = threadIdx.x & 63;
    int qh = q / 96, qw = q % 96;
#pragma unroll
    for (int t = 0; t < 5; ++t) {
        int k = lane + t * 64;
        if (k < 288) {
            int c = k / 9, r = k % 9;
            int y = qh + r / 3 - 1, x = qw + r % 3 - 1;
            float v = (y >= 0 && y < 96 && x >= 0 && x < 96) ? match[c * 9216 + y * 96 + x] : 0.f;
            xp[(size_t)q * 288 + k] = (_Float16)v;
        }
    }
}

// wn[l][c*9+kh*3+kw] = 10 * patch / max(||patch||, 1e-4), fp16.  1 wave per l.
__global__ void build_wn(const float* __restrict__ ref, _Float16* __restrict__ wn) {
    int l = blockIdx.x;  // 2304
    int oh = l / 48, ow = l % 48;
    int lane = threadIdx.x;  // 64
    float vals[5];
    float ss = 0.f;
#pragma unroll
    for (int t = 0; t < 5; ++t) {
        int i = lane + t * 64;
        float v = 0.f;
        if (i < 288) {
            int c = i / 9, r = i % 9, kh = r / 3, kw = r % 3;
            int y = oh + kh - 1, x = ow + kw - 1;
            v = (y >= 0 && y < 48 && x >= 0 && x < 48) ? ref[c * 2304 + y * 48 + x] : 0.f;
        }
        vals[t] = v;
        ss += v * v;
    }
#pragma unroll
    for (int d = 32; d; d >>= 1) ss += __shfl_xor(ss, d);
    float norm = sqrtf(ss);
    norm = norm < 1e-4f ? 1e-4f : norm;
    float inv = 10.f / norm;  // fold SOFTMAX_SCALE here
#pragma unroll
    for (int t = 0; t < 5; ++t) {
        int i = lane + t * 64;
        if (i < 288) wn[(size_t)l * 288 + i] = (_Float16)(vals[t] * inv);
    }
}

// Wt[row=(o*36+i*6+j)][l=(lh*48+lw)] = embed[o][2lh+i-2][2lw+j-2] (zero pad), fp16
__global__ void build_Wt(const float* __restrict__ embed, _Float16* __restrict__ Wt) {
    int idx = blockIdx.x * 256 + threadIdx.x;
    if (idx >= 2304 * 2304) return;
    int row = idx / 2304, l = idx % 2304;
    int o = row / 36, rem = row % 36, i = rem / 6, j = rem % 6;
    int lh = l / 48, lw = l % 48;
    int y = 2 * lh + i - 2, x = 2 * lw + j - 2;
    float v = (y >= 0 && y < 96 && x >= 0 && x < 96) ? embed[o * 9216 + y * 96 + x] : 0.f;
    Wt[idx] = (_Float16)v;
}

// row softmax over l=2304 per q, writes fp16 normalized weights
__global__ __launch_bounds__(256) void softmax_rows(const float* __restrict__ S,
                                                    _Float16* __restrict__ yi) {
    int q = blockIdx.x;
    const float* row = S + (size_t)q * 2304;
    int tid = threadIdx.x;
    float v[9];
    float m = -1e30f;
#pragma unroll
    for (int t = 0; t < 9; ++t) {
        v[t] = row[tid + t * 256];
        m = fmaxf(m, v[t]);
    }
    __shared__ float red[8];
#pragma unroll
    for (int d = 32; d; d >>= 1) m = fmaxf(m, __shfl_xor(m, d));
    if ((tid & 63) == 0) red[tid >> 6] = m;
    __syncthreads();
    m = fmaxf(fmaxf(red[0], red[1]), fmaxf(red[2], red[3]));
    float s = 0.f;
#pragma unroll
    for (int t = 0; t < 9; ++t) {
        v[t] = expf(v[t] - m);
        s += v[t];
    }
#pragma unroll
    for (int d = 32; d; d >>= 1) s += __shfl_xor(s, d);
    __syncthreads();
    if ((tid & 63) == 0) red[(tid >> 6) + 4] = s;
    __syncthreads();
    s = red[4] + red[5] + red[6] + red[7];
    float inv = 1.f / s;
    _Float16* orow = yi + (size_t)q * 2304;
#pragma unroll
    for (int t = 0; t < 9; ++t) orow[tid + t * 256] = (_Float16)(v[t] * inv);
}

// ---------------------------------------------------------------- MFMA GEMM
// C[M][N] = sum_k A[M][K] * B[N][K]  (K-contiguous fp16), fp32 accum.
// MODE 0: fp32 store.  MODE 1: fp16 store.  MODE 2: rows<64, (acc+bias[row])/6.
// Staging: global_load_lds width-16. Tile = 128 rows x 32 halves = 8 x 1KB chunks
// per matrix; each wave issues 2 A-chunks + 2 B-chunks (c = wave*2 + r, r<2).
// XOR swizzle slot = cc ^ ((row>>1)&3) keeps ds_read_b128 at 2-way/bank (free).
template <int MODE>
__global__ __launch_bounds__(256) void gemm16(const _Float16* __restrict__ A,
                                              const _Float16* __restrict__ B, int M, int N, int K,
                                              void* __restrict__ outv,
                                              const float* __restrict__ bias) {
    __shared__ _Float16 As[128 * 32];
    __shared__ _Float16 Bs[128 * 32];
    int tid = threadIdx.x;
    int wave = tid >> 6, lane = tid & 63;
    int wm = wave >> 1, wn_ = wave & 1;  // 2x2 wave grid, 64x64 per wave
    int quad = lane >> 4, mrow = lane & 15;
    int m0 = blockIdx.y * 128, n0 = blockIdx.x * 128;
    int lrow = lane >> 2, lslot = lane & 3;
    float4v acc[4][4] = {};

    for (int k0 = 0; k0 < K; k0 += 32) {
        // chunk c = rows [c*16, c*16+16); lane writes LDS at chunk_base + lane*16B
        // (hardware layout), so source element = (row = c*16 + lane/4,
        //  cc = (lane&3) ^ ((row>>1)&3)) — the inverse of the read swizzle.
#pragma unroll
        for (int r = 0; r < 2; ++r) {
            int c = wave * 2 + r;  // 0..7 — exactly 8 chunks per matrix
            int row = c * 16 + lrow;
            int cc = lslot ^ ((row >> 1) & 3);
            const _Float16* ga = A + (size_t)(m0 + row) * K + k0 + cc * 8;
            const _Float16* gb = B + (size_t)(n0 + row) * K + k0 + cc * 8;
            __builtin_amdgcn_global_load_lds(
                (const __attribute__((address_space(1))) unsigned int*)ga,
                (__attribute__((address_space(3))) unsigned int*)&As[c * 512], 16, 0, 0);
            __builtin_amdgcn_global_load_lds(
                (const __attribute__((address_space(1))) unsigned int*)gb,
                (__attribute__((address_space(3))) unsigned int*)&Bs[c * 512], 16, 0, 0);
        }
        __syncthreads();
        half8 af[4], bf[4];
#pragma unroll
        for (int t = 0; t < 4; ++t) {
            int arow = wm * 64 + t * 16 + mrow;
            af[t] = *(const half8*)&As[arow * 32 + (quad ^ ((arow >> 1) & 3)) * 8];
            int brow = wn_ * 64 + t * 16 + mrow;
            bf[t] = *(const half8*)&Bs[brow * 32 + (quad ^ ((brow >> 1) & 3)) * 8];
        }
#pragma unroll
        for (int i = 0; i < 4; ++i)
#pragma unroll
            for (int j = 0; j < 4; ++j)
                acc[i][j] = __builtin_amdgcn_mfma_f32_16x16x32_f16(af[i], bf[j], acc[i][j], 0, 0, 0);
        __syncthreads();
    }

    // epilogue: D row m = quad*4+r (M dim), col n = lane&15 (N dim)
#pragma unroll
    for (int i = 0; i < 4; ++i)
#pragma unroll
        for (int j = 0; j < 4; ++j)
#pragma unroll
            for (int r = 0; r < 4; ++r) {
                int row = m0 + wm * 64 + i * 16 + quad * 4 + r;
                int col = n0 + wn_ * 64 + j * 16 + mrow;
                float v = acc[i][j][r];
                if (MODE == 0) {
                    ((float*)outv)[(size_t)row * N + col] = v;
                } else if (MODE == 1) {
                    ((_Float16*)outv)[(size_t)row * N + col] = (_Float16)v;
                } else {
                    if (row < 64)
                        ((float*)outv)[(size_t)row * N + col] = (v + bias[row]) * (1.f / 6.f);
                }
            }
}

// ---------------------------------------------------------------- tail

// gather (inverse of tconv scatter): yth[o][Y][X] = sum_{i==Y%2, j==X%2 (mod 2)}
//   Z[(o*36+i*6+j)][h*96+w]  with h=(Y+2-i)/2, w=(X+2-j)/2 in range. fp16 in/out.
__global__ void gather_yt(const _Float16* __restrict__ Z, _Float16* __restrict__ yth) {
    int idx = blockIdx.x * 256 + threadIdx.x;
    if (idx >= 64 * 192 * 192) return;
    int o = idx / 36864, r = idx % 36864, Y = r / 192, X = r % 192;
    float s = 0.f;
    for (int i = Y & 1; i < 6; i += 2) {
        int h2 = Y + 2 - i;
        if (h2 < 0) continue;
        int h = h2 >> 1;
        if (h >= 96) continue;
        for (int j = X & 1; j < 6; j += 2) {
            int w2 = X + 2 - j;
            if (w2 < 0) continue;
            int w = w2 >> 1;
            if (w >= 96) continue;
            s += (float)Z[(size_t)(o * 36 + i * 6 + j) * 9216 + h * 96 + w];
        }
    }
    yth[idx] = (_Float16)s;
}

// im2col for the down conv (3x3, stride 2, pad 1), wave per q, lane-contiguous k:
// P[q=(y*96+x)][k=o*9+dy*3+dx] = yth[o][2y-1+dy][2x-1+dx] (zero pad), fp16.
__global__ __launch_bounds__(256) void build_P(const _Float16* __restrict__ yth,
                                               _Float16* __restrict__ P) {
    int q = blockIdx.x * 4 + (threadIdx.x >> 6);
    int lane = threadIdx.x & 63;
    int y = q / 96, x = q % 96;
#pragma unroll
    for (int t = 0; t < 9; ++t) {
        int k = lane + t * 64;
        int o = k / 9, r = k % 9;
        int Y = 2 * y - 1 + r / 3, X = 2 * x - 1 + r % 3;
        _Float16 v = (_Float16)0.f;
        if (Y >= 0 && Y < 192 && X >= 0 && X < 192) v = yth[o * 36864 + Y * 192 + X];
        P[(size_t)q * 576 + k] = v;
    }
}

// Wdh[op][k] fp16, rows 64..127 zero-padded (so the 128-row GEMM tile is safe)
__global__ void build_Wdh(const float* __restrict__ Wd, _Float16* __restrict__ Wdh) {
    int idx = blockIdx.x * 256 + threadIdx.x;
    if (idx >= 128 * 576) return;
    int op = idx / 576;
    Wdh[idx] = (_Float16)(op < 64 ? Wd[idx] : 0.f);
}

// ---------------------------------------------------------------- launch

extern "C" void kernel_launch(void* const* d_in, const int* in_sizes, int n_in,
                              void* d_out, int out_size, void* d_ws, size_t ws_size,
                              hipStream_t stream) {
    const float* x = (const float*)d_in[0];
    const float* W1 = (const float*)d_in[1];
    const float* b1 = (const float*)d_in[2];
    const float* a1 = (const float*)d_in[3];
    const float* W2 = (const float*)d_in[4];
    const float* b2 = (const float*)d_in[5];
    const float* a2 = (const float*)d_in[6];
    const float* Wa = (const float*)d_in[7];
    const float* ba = (const float*)d_in[8];
    const float* aa = (const float*)d_in[9];
    const float* Wd = (const float*)d_in[10];
    const float* bd = (const float*)d_in[11];
    float* out = (float*)d_out;

    char* ws = (char*)d_ws;
    float* S = (float*)ws;           ws += 84934656;  // [9216][2304] fp32 logits; Z fp16 aliases
    _Float16* yi = (_Float16*)ws;    ws += 42467328;  // [9216][2304] fp16 softmax; P aliases
    _Float16* Wt = (_Float16*)ws;    ws += 10616832;  // [2304][2304] fp16; yth aliases
    _Float16* xp = (_Float16*)ws;    ws += 5308416;   // [9216][288] fp16
    _Float16* wn = (_Float16*)ws;    ws += 1327104;   // [2304][288] fp16 (x10 folded)
    float* embed2 = (float*)ws;      ws += 4718592;   // [2][64][96][96]
    float* match2 = (float*)ws;      ws += 2359296;   // [2][32][96][96]
    float* refb2 = (float*)ws;       ws += 589824;    // [2][32][48][48]
    _Float16* Wdh = (_Float16*)ws;   ws += 147456;    // [128][576] fp16 (rows 64+ zero)
    // aliases (writer runs strictly after the last read of the aliased buffer)
    _Float16* Z = (_Float16*)S;   // [2304][9216] fp16 — after softmax consumed S
    _Float16* P = yi;             // [9216][576] fp16 — after GEMM2 consumed yi
    _Float16* yth = Wt;           // [64][192][192] fp16 — after GEMM2 consumed Wt
    // total ~152.5 MB (< 158.6 MB proven in round 1)

    build_Wdh<<<288, 256, 0, stream>>>(Wd, Wdh);
    // batched front: both images at once (tiny grids otherwise underfill 256 CUs)
    conv_embed_match<<<dim3(36, 6, 2), 256, 0, stream>>>(x, Wa, ba, aa, W1, b1, a1, embed2, match2);
    conv_ref_pooled<<<dim3(9, 2, 2), 256, 0, stream>>>(x, W2, b2, a2, refb2);

    for (int b = 0; b < 2; ++b) {
        float* outb = out + (size_t)b * 64 * 9216;
        const float* embed = embed2 + (size_t)b * 64 * 9216;
        const float* match = match2 + (size_t)b * 32 * 9216;
        const float* refb = refb2 + (size_t)b * 32 * 2304;

        build_xp<<<2304, 256, 0, stream>>>(match, xp);
        build_wn<<<2304, 64, 0, stream>>>(refb, wn);
        build_Wt<<<20736, 256, 0, stream>>>(embed, Wt);

        // GEMM1: S[q][l] = <xp[q], wn[l]> (x10 folded into wn)
        gemm16<0><<<dim3(18, 72), 256, 0, stream>>>(xp, wn, 9216, 2304, 288, S, nullptr);
        softmax_rows<<<9216, 256, 0, stream>>>(S, yi);

        // GEMM2: Z[(oij)][q] = sum_l Wt[(oij)][l] * yi[q][l]  (fp16 store into S-alias)
        gemm16<1><<<dim3(72, 18), 256, 0, stream>>>(Wt, yi, 2304, 9216, 2304, Z, nullptr);

        gather_yt<<<9216, 256, 0, stream>>>(Z, yth);
        build_P<<<2304, 256, 0, stream>>>(yth, P);
        // GEMM3 (down conv): out[op][q] = (sum_k Wdh[op][k] P[q][k] + bd[op]) / 6
        gemm16<2><<<dim3(72, 1), 256, 0, stream>>>(Wdh, P, 128, 9216, 576, outb, bd);
    }
}

// Round 10
// 627.323 us; speedup vs baseline: 7.0377x; 1.0183x over previous
//
#include <hip/hip_runtime.h>

typedef _Float16 half8 __attribute__((ext_vector_type(8)));
typedef float float4v __attribute__((ext_vector_type(4)));

// ---------------------------------------------------------------- front (batched over z)

// fused conv1x1+prelu for embed (64 ch, Wa) and match (32 ch, W1); x read once per
// co-chunk. grid (36, 6, B): chunks 0-3 -> embed co 0..63, chunks 4-5 -> match co 0..31.
__global__ __launch_bounds__(256) void conv_embed_match(
    const float* __restrict__ x, const float* __restrict__ Wa, const float* __restrict__ ba,
    const float* __restrict__ aa, const float* __restrict__ W1, const float* __restrict__ b1,
    const float* __restrict__ a1, float* __restrict__ embed2, float* __restrict__ match2) {
    int b = blockIdx.z;
    const float* xb = x + (size_t)b * 64 * 9216;
    int p = blockIdx.x * 256 + threadIdx.x;  // 9216 pixels
    int chunk = blockIdx.y;
    float xin[64];
#pragma unroll
    for (int ci = 0; ci < 64; ++ci) xin[ci] = xb[ci * 9216 + p];
    bool isE = chunk < 4;
    int co0 = (isE ? chunk : chunk - 4) * 16;
    const float* W = isE ? Wa : W1;
    const float* bb = isE ? ba : b1;
    float alpha = (isE ? aa : a1)[0];
    float* dst = isE ? (embed2 + (size_t)b * 64 * 9216) : (match2 + (size_t)b * 32 * 9216);
#pragma unroll
    for (int c = 0; c < 16; ++c) {
        int co = co0 + c;
        float s = bb[co];
#pragma unroll
        for (int ci = 0; ci < 64; ++ci) s += W[co * 64 + ci] * xin[ci];
        dst[co * 9216 + p] = s >= 0.f ? s : alpha * s;
    }
}

// ref conv with inline 2x2 mean pool. grid (9, 2, B).
__global__ __launch_bounds__(256) void conv_ref_pooled(
    const float* __restrict__ x, const float* __restrict__ W2, const float* __restrict__ b2,
    const float* __restrict__ a2, float* __restrict__ refb2) {
    int b = blockIdx.z;
    const float* xb = x + (size_t)b * 64 * 9216;
    int p = blockIdx.x * 256 + threadIdx.x;  // 0..2303
    int ph = p / 48, pw = p % 48;
    int co0 = blockIdx.y * 16;
    float xin[64];
#pragma unroll
    for (int ci = 0; ci < 64; ++ci) {
        const float* q = xb + ci * 9216 + ph * 2 * 96 + pw * 2;
        xin[ci] = 0.25f * (q[0] + q[1] + q[96] + q[97]);
    }
    float alpha = a2[0];
    float* dst = refb2 + (size_t)b * 32 * 2304;
#pragma unroll
    for (int c = 0; c < 16; ++c) {
        int co = co0 + c;
        float s = b2[co];
#pragma unroll
        for (int ci = 0; ci < 64; ++ci) s += W2[co * 64 + ci] * xin[ci];
        dst[co * 2304 + p] = s >= 0.f ? s : alpha * s;
    }
}

// ---------------------------------------------------------------- per-batch builds

// xp[q][k=c*9+kh*3+kw] = match[c][qh+kh-1][qw+kw-1] (zero pad), fp16.
__global__ __launch_bounds__(256) void build_xp(const float* __restrict__ match,
                                                _Float16* __restrict__ xp) {
    int q = blockIdx.x * 4 + (threadIdx.x >> 6);
    int lane = threadIdx.x & 63;
    int qh = q / 96, qw = q % 96;
#pragma unroll
    for (int t = 0; t < 5; ++t) {
        int k = lane + t * 64;
        if (k < 288) {
            int c = k / 9, r = k % 9;
            int y = qh + r / 3 - 1, x = qw + r % 3 - 1;
            float v = (y >= 0 && y < 96 && x >= 0 && x < 96) ? match[c * 9216 + y * 96 + x] : 0.f;
            xp[(size_t)q * 288 + k] = (_Float16)v;
        }
    }
}

// wn[l][c*9+kh*3+kw] = 10 * patch / max(||patch||, 1e-4), fp16.  1 wave per l.
__global__ void build_wn(const float* __restrict__ ref, _Float16* __restrict__ wn) {
    int l = blockIdx.x;  // 2304
    int oh = l / 48, ow = l % 48;
    int lane = threadIdx.x;  // 64
    float vals[5];
    float ss = 0.f;
#pragma unroll
    for (int t = 0; t < 5; ++t) {
        int i = lane + t * 64;
        float v = 0.f;
        if (i < 288) {
            int c = i / 9, r = i % 9, kh = r / 3, kw = r % 3;
            int y = oh + kh - 1, x = ow + kw - 1;
            v = (y >= 0 && y < 48 && x >= 0 && x < 48) ? ref[c * 2304 + y * 48 + x] : 0.f;
        }
        vals[t] = v;
        ss += v * v;
    }
#pragma unroll
    for (int d = 32; d; d >>= 1) ss += __shfl_xor(ss, d);
    float norm = sqrtf(ss);
    norm = norm < 1e-4f ? 1e-4f : norm;
    float inv = 10.f / norm;  // fold SOFTMAX_SCALE here
#pragma unroll
    for (int t = 0; t < 5; ++t) {
        int i = lane + t * 64;
        if (i < 288) wn[(size_t)l * 288 + i] = (_Float16)(vals[t] * inv);
    }
}

// Wt[row=(o*36+i*6+j)][l=(lh*48+lw)] = embed[o][2lh+i-2][2lw+j-2] (zero pad), fp16
__global__ void build_Wt(const float* __restrict__ embed, _Float16* __restrict__ Wt) {
    int idx = blockIdx.x * 256 + threadIdx.x;
    if (idx >= 2304 * 2304) return;
    int row = idx / 2304, l = idx % 2304;
    int o = row / 36, rem = row % 36, i = rem / 6, j = rem % 6;
    int lh = l / 48, lw = l % 48;
    int y = 2 * lh + i - 2, x = 2 * lw + j - 2;
    float v = (y >= 0 && y < 96 && x >= 0 && x < 96) ? embed[o * 9216 + y * 96 + x] : 0.f;
    Wt[idx] = (_Float16)v;
}

// row softmax over l=2304 per q, writes fp16 normalized weights
__global__ __launch_bounds__(256) void softmax_rows(const float* __restrict__ S,
                                                    _Float16* __restrict__ yi) {
    int q = blockIdx.x;
    const float* row = S + (size_t)q * 2304;
    int tid = threadIdx.x;
    float v[9];
    float m = -1e30f;
#pragma unroll
    for (int t = 0; t < 9; ++t) {
        v[t] = row[tid + t * 256];
        m = fmaxf(m, v[t]);
    }
    __shared__ float red[8];
#pragma unroll
    for (int d = 32; d; d >>= 1) m = fmaxf(m, __shfl_xor(m, d));
    if ((tid & 63) == 0) red[tid >> 6] = m;
    __syncthreads();
    m = fmaxf(fmaxf(red[0], red[1]), fmaxf(red[2], red[3]));
    float s = 0.f;
#pragma unroll
    for (int t = 0; t < 9; ++t) {
        v[t] = expf(v[t] - m);
        s += v[t];
    }
#pragma unroll
    for (int d = 32; d; d >>= 1) s += __shfl_xor(s, d);
    __syncthreads();
    if ((tid & 63) == 0) red[(tid >> 6) + 4] = s;
    __syncthreads();
    s = red[4] + red[5] + red[6] + red[7];
    float inv = 1.f / s;
    _Float16* orow = yi + (size_t)q * 2304;
#pragma unroll
    for (int t = 0; t < 9; ++t) orow[tid + t * 256] = (_Float16)(v[t] * inv);
}

// ---------------------------------------------------------------- MFMA GEMM (BK=32)
// C[M][N] = sum_k A[M][K] * B[N][K]  (K-contiguous fp16), fp32 accum.
// MODE 0: fp32 store.  MODE 2: rows<64, (acc+bias[row])/6.
// Used for GEMM1 (K=288) and GEMM3 (K=576).
template <int MODE>
__global__ __launch_bounds__(256) void gemm16(const _Float16* __restrict__ A,
                                              const _Float16* __restrict__ B, int M, int N, int K,
                                              void* __restrict__ outv,
                                              const float* __restrict__ bias) {
    __shared__ _Float16 As[128 * 32];
    __shared__ _Float16 Bs[128 * 32];
    int tid = threadIdx.x;
    int wave = tid >> 6, lane = tid & 63;
    int wm = wave >> 1, wn_ = wave & 1;  // 2x2 wave grid, 64x64 per wave
    int quad = lane >> 4, mrow = lane & 15;
    int m0 = blockIdx.y * 128, n0 = blockIdx.x * 128;
    int lrow = lane >> 2, lslot = lane & 3;
    float4v acc[4][4] = {};

    for (int k0 = 0; k0 < K; k0 += 32) {
#pragma unroll
        for (int r = 0; r < 2; ++r) {
            int c = wave * 2 + r;  // 0..7 — 8 x 1KB chunks per matrix
            int row = c * 16 + lrow;
            int cc = lslot ^ ((row >> 1) & 3);
            const _Float16* ga = A + (size_t)(m0 + row) * K + k0 + cc * 8;
            const _Float16* gb = B + (size_t)(n0 + row) * K + k0 + cc * 8;
            __builtin_amdgcn_global_load_lds(
                (const __attribute__((address_space(1))) unsigned int*)ga,
                (__attribute__((address_space(3))) unsigned int*)&As[c * 512], 16, 0, 0);
            __builtin_amdgcn_global_load_lds(
                (const __attribute__((address_space(1))) unsigned int*)gb,
                (__attribute__((address_space(3))) unsigned int*)&Bs[c * 512], 16, 0, 0);
        }
        __syncthreads();
        half8 af[4], bf[4];
#pragma unroll
        for (int t = 0; t < 4; ++t) {
            int arow = wm * 64 + t * 16 + mrow;
            af[t] = *(const half8*)&As[arow * 32 + (quad ^ ((arow >> 1) & 3)) * 8];
            int brow = wn_ * 64 + t * 16 + mrow;
            bf[t] = *(const half8*)&Bs[brow * 32 + (quad ^ ((brow >> 1) & 3)) * 8];
        }
#pragma unroll
        for (int i = 0; i < 4; ++i)
#pragma unroll
            for (int j = 0; j < 4; ++j)
                acc[i][j] = __builtin_amdgcn_mfma_f32_16x16x32_f16(af[i], bf[j], acc[i][j], 0, 0, 0);
        __syncthreads();
    }

#pragma unroll
    for (int i = 0; i < 4; ++i)
#pragma unroll
        for (int j = 0; j < 4; ++j)
#pragma unroll
            for (int r = 0; r < 4; ++r) {
                int row = m0 + wm * 64 + i * 16 + quad * 4 + r;
                int col = n0 + wn_ * 64 + j * 16 + mrow;
                float v = acc[i][j][r];
                if (MODE == 0) {
                    ((float*)outv)[(size_t)row * N + col] = v;
                } else {
                    if (row < 64)
                        ((float*)outv)[(size_t)row * N + col] = (v + bias[row]) * (1.f / 6.f);
                }
            }
}

// ---------------------------------------------------------------- MFMA GEMM (BK=64)
// Same contract, fp16 output, K % 64 == 0. 32 MFMA per barrier pair (vs 16 at
// BK=32) — halves barrier/staging overhead per MFMA. LDS 2x16 KB (2 blocks/CU
// unchanged). Rows are 128 B = 8 x 16B slots; phys slot = src ^ (row&7):
// a wave's ds_read_b128 hits each 4-bank group with 8 lanes = 2/bank (free).
__global__ __launch_bounds__(256) void gemm16_bk64(const _Float16* __restrict__ A,
                                                   const _Float16* __restrict__ B,
                                                   int M, int N, int K,
                                                   _Float16* __restrict__ out) {
    __shared__ _Float16 As[128 * 64];
    __shared__ _Float16 Bs[128 * 64];
    int tid = threadIdx.x;
    int wave = tid >> 6, lane = tid & 63;
    int wm = wave >> 1, wn_ = wave & 1;  // 2x2 wave grid, 64x64 per wave
    int quad = lane >> 4, mrow = lane & 15;
    int m0 = blockIdx.y * 128, n0 = blockIdx.x * 128;
    int crow = lane >> 3, cslot = lane & 7;  // staging: 8 rows x 8 slots per 1KB chunk
    float4v acc[4][4] = {};

    for (int k0 = 0; k0 < K; k0 += 64) {
        // 16 chunks of 1KB per matrix; wave w issues chunks w*4..w*4+3 of each.
        // chunk c covers rows c*8..c*8+8. lane writes chunk_base + lane*16B =
        // row*128B + cslot*16B, so source slot = cslot ^ (row&7).
#pragma unroll
        for (int r = 0; r < 4; ++r) {
            int c = wave * 4 + r;        // 0..15
            int row = c * 8 + crow;      // 0..127
            int ss = cslot ^ (row & 7);
            const _Float16* ga = A + (size_t)(m0 + row) * K + k0 + ss * 8;
            const _Float16* gb = B + (size_t)(n0 + row) * K + k0 + ss * 8;
            __builtin_amdgcn_global_load_lds(
                (const __attribute__((address_space(1))) unsigned int*)ga,
                (__attribute__((address_space(3))) unsigned int*)&As[c * 512],  // 512 halves = 1KB
                16, 0, 0);
            __builtin_amdgcn_global_load_lds(
                (const __attribute__((address_space(1))) unsigned int*)gb,
                (__attribute__((address_space(3))) unsigned int*)&Bs[c * 512], 16, 0, 0);
        }
        __syncthreads();
        // fragment for k-band d (0,1): halves [d*32 + quad*8 .. +8) = src slot d*4+quad
        half8 af[2][4], bf[2][4];
#pragma unroll
        for (int d = 0; d < 2; ++d)
#pragma unroll
            for (int t = 0; t < 4; ++t) {
                int ar = wm * 64 + t * 16 + mrow;
                af[d][t] = *(const half8*)&As[ar * 64 + (((d * 4 + quad) ^ (ar & 7)) * 8)];
                int br = wn_ * 64 + t * 16 + mrow;
                bf[d][t] = *(const half8*)&Bs[br * 64 + (((d * 4 + quad) ^ (br & 7)) * 8)];
            }
#pragma unroll
        for (int d = 0; d < 2; ++d)
#pragma unroll
            for (int i = 0; i < 4; ++i)
#pragma unroll
                for (int j = 0; j < 4; ++j)
                    acc[i][j] =
                        __builtin_amdgcn_mfma_f32_16x16x32_f16(af[d][i], bf[d][j], acc[i][j], 0, 0, 0);
        __syncthreads();
    }

    // epilogue: row m = quad*4+r, col = lane&15 — fp16 store
#pragma unroll
    for (int i = 0; i < 4; ++i)
#pragma unroll
        for (int j = 0; j < 4; ++j)
#pragma unroll
            for (int r = 0; r < 4; ++r) {
                int row = m0 + wm * 64 + i * 16 + quad * 4 + r;
                int col = n0 + wn_ * 64 + j * 16 + mrow;
                out[(size_t)row * N + col] = (_Float16)acc[i][j][r];
            }
}

// ---------------------------------------------------------------- tail

// gather (inverse of tconv scatter): yth[o][Y][X] = sum_{i==Y%2, j==X%2 (mod 2)}
//   Z[(o*36+i*6+j)][h*96+w],  h=(Y+2-i)/2, w=(X+2-j)/2 in range. fp16 in/out.
__global__ void gather_yt(const _Float16* __restrict__ Z, _Float16* __restrict__ yth) {
    int idx = blockIdx.x * 256 + threadIdx.x;
    if (idx >= 64 * 192 * 192) return;
    int o = idx / 36864, r = idx % 36864, Y = r / 192, X = r % 192;
    float s = 0.f;
    for (int i = Y & 1; i < 6; i += 2) {
        int h2 = Y + 2 - i;
        if (h2 < 0) continue;
        int h = h2 >> 1;
        if (h >= 96) continue;
        for (int j = X & 1; j < 6; j += 2) {
            int w2 = X + 2 - j;
            if (w2 < 0) continue;
            int w = w2 >> 1;
            if (w >= 96) continue;
            s += (float)Z[(size_t)(o * 36 + i * 6 + j) * 9216 + h * 96 + w];
        }
    }
    yth[idx] = (_Float16)s;
}

// im2col for the down conv (3x3, stride 2, pad 1), wave per q, lane-contiguous k.
__global__ __launch_bounds__(256) void build_P(const _Float16* __restrict__ yth,
                                               _Float16* __restrict__ P) {
    int q = blockIdx.x * 4 + (threadIdx.x >> 6);
    int lane = threadIdx.x & 63;
    int y = q / 96, x = q % 96;
#pragma unroll
    for (int t = 0; t < 9; ++t) {
        int k = lane + t * 64;
        int o = k / 9, r = k % 9;
        int Y = 2 * y - 1 + r / 3, X = 2 * x - 1 + r % 3;
        _Float16 v = (_Float16)0.f;
        if (Y >= 0 && Y < 192 && X >= 0 && X < 192) v = yth[o * 36864 + Y * 192 + X];
        P[(size_t)q * 576 + k] = v;
    }
}

// Wdh[op][k] fp16, rows 64..127 zero-padded
__global__ void build_Wdh(const float* __restrict__ Wd, _Float16* __restrict__ Wdh) {
    int idx = blockIdx.x * 256 + threadIdx.x;
    if (idx >= 128 * 576) return;
    int op = idx / 576;
    Wdh[idx] = (_Float16)(op < 64 ? Wd[idx] : 0.f);
}

// ---------------------------------------------------------------- launch

extern "C" void kernel_launch(void* const* d_in, const int* in_sizes, int n_in,
                              void* d_out, int out_size, void* d_ws, size_t ws_size,
                              hipStream_t stream) {
    const float* x = (const float*)d_in[0];
    const float* W1 = (const float*)d_in[1];
    const float* b1 = (const float*)d_in[2];
    const float* a1 = (const float*)d_in[3];
    const float* W2 = (const float*)d_in[4];
    const float* b2 = (const float*)d_in[5];
    const float* a2 = (const float*)d_in[6];
    const float* Wa = (const float*)d_in[7];
    const float* ba = (const float*)d_in[8];
    const float* aa = (const float*)d_in[9];
    const float* Wd = (const float*)d_in[10];
    const float* bd = (const float*)d_in[11];
    float* out = (float*)d_out;

    char* ws = (char*)d_ws;
    float* S = (float*)ws;           ws += 84934656;  // [9216][2304] fp32 logits; Z fp16 aliases
    _Float16* yi = (_Float16*)ws;    ws += 42467328;  // [9216][2304] fp16 softmax; P aliases
    _Float16* Wt = (_Float16*)ws;    ws += 10616832;  // [2304][2304] fp16; yth aliases
    _Float16* xp = (_Float16*)ws;    ws += 5308416;   // [9216][288] fp16
    _Float16* wn = (_Float16*)ws;    ws += 1327104;   // [2304][288] fp16 (x10 folded)
    float* embed2 = (float*)ws;      ws += 4718592;   // [2][64][96][96]
    float* match2 = (float*)ws;      ws += 2359296;   // [2][32][96][96]
    float* refb2 = (float*)ws;       ws += 589824;    // [2][32][48][48]
    _Float16* Wdh = (_Float16*)ws;   ws += 147456;    // [128][576] fp16 (rows 64+ zero)
    // aliases (writer runs strictly after the last read of the aliased buffer)
    _Float16* Z = (_Float16*)S;   // [2304][9216] fp16 — after softmax consumed S
    _Float16* P = yi;             // [9216][576] fp16 — after GEMM2 consumed yi
    _Float16* yth = Wt;           // [64][192][192] fp16 — after GEMM2 consumed Wt
    // total ~152.5 MB (< 158.6 MB proven in round 1)

    build_Wdh<<<288, 256, 0, stream>>>(Wd, Wdh);
    // batched front: both images at once (tiny grids otherwise underfill 256 CUs)
    conv_embed_match<<<dim3(36, 6, 2), 256, 0, stream>>>(x, Wa, ba, aa, W1, b1, a1, embed2, match2);
    conv_ref_pooled<<<dim3(9, 2, 2), 256, 0, stream>>>(x, W2, b2, a2, refb2);

    for (int b = 0; b < 2; ++b) {
        float* outb = out + (size_t)b * 64 * 9216;
        const float* embed = embed2 + (size_t)b * 64 * 9216;
        const float* match = match2 + (size_t)b * 32 * 9216;
        const float* refb = refb2 + (size_t)b * 32 * 2304;

        build_xp<<<2304, 256, 0, stream>>>(match, xp);
        build_wn<<<2304, 64, 0, stream>>>(refb, wn);
        build_Wt<<<20736, 256, 0, stream>>>(embed, Wt);

        // GEMM1 (BK=32): S[q][l] = <xp[q], wn[l]> (x10 folded into wn)
        gemm16<0><<<dim3(18, 72), 256, 0, stream>>>(xp, wn, 9216, 2304, 288, S, nullptr);
        softmax_rows<<<9216, 256, 0, stream>>>(S, yi);

        // GEMM2 (BK=64): Z[(oij)][q] = sum_l Wt[(oij)][l] * yi[q][l]  (fp16 store)
        gemm16_bk64<<<dim3(72, 18), 256, 0, stream>>>(Wt, yi, 2304, 9216, 2304, Z);

        gather_yt<<<9216, 256, 0, stream>>>(Z, yth);
        build_P<<<2304, 256, 0, stream>>>(yth, P);
        // GEMM3 (down conv): out[op][q] = (sum_k Wdh[op][k] P[q][k] + bd[op]) / 6
        gemm16<2><<<dim3(72, 1), 256, 0, stream>>>(Wdh, P, 128, 9216, 576, outb, bd);
    }
}

// Round 11
// 611.141 us; speedup vs baseline: 7.2240x; 1.0265x over previous
//
#include <hip/hip_runtime.h>

typedef _Float16 half8 __attribute__((ext_vector_type(8)));
typedef float float4v __attribute__((ext_vector_type(4)));

// ---------------------------------------------------------------- front (batched over z)

// fused conv1x1+prelu for embed (64 ch, Wa) and match (32 ch, W1); x read once per
// co-chunk. grid (36, 6, B): chunks 0-3 -> embed co 0..63, chunks 4-5 -> match co 0..31.
__global__ __launch_bounds__(256) void conv_embed_match(
    const float* __restrict__ x, const float* __restrict__ Wa, const float* __restrict__ ba,
    const float* __restrict__ aa, const float* __restrict__ W1, const float* __restrict__ b1,
    const float* __restrict__ a1, float* __restrict__ embed2, float* __restrict__ match2) {
    int b = blockIdx.z;
    const float* xb = x + (size_t)b * 64 * 9216;
    int p = blockIdx.x * 256 + threadIdx.x;  // 9216 pixels
    int chunk = blockIdx.y;
    float xin[64];
#pragma unroll
    for (int ci = 0; ci < 64; ++ci) xin[ci] = xb[ci * 9216 + p];
    bool isE = chunk < 4;
    int co0 = (isE ? chunk : chunk - 4) * 16;
    const float* W = isE ? Wa : W1;
    const float* bb = isE ? ba : b1;
    float alpha = (isE ? aa : a1)[0];
    float* dst = isE ? (embed2 + (size_t)b * 64 * 9216) : (match2 + (size_t)b * 32 * 9216);
#pragma unroll
    for (int c = 0; c < 16; ++c) {
        int co = co0 + c;
        float s = bb[co];
#pragma unroll
        for (int ci = 0; ci < 64; ++ci) s += W[co * 64 + ci] * xin[ci];
        dst[co * 9216 + p] = s >= 0.f ? s : alpha * s;
    }
}

// ref conv with inline 2x2 mean pool. grid (9, 2, B).
__global__ __launch_bounds__(256) void conv_ref_pooled(
    const float* __restrict__ x, const float* __restrict__ W2, const float* __restrict__ b2,
    const float* __restrict__ a2, float* __restrict__ refb2) {
    int b = blockIdx.z;
    const float* xb = x + (size_t)b * 64 * 9216;
    int p = blockIdx.x * 256 + threadIdx.x;  // 0..2303
    int ph = p / 48, pw = p % 48;
    int co0 = blockIdx.y * 16;
    float xin[64];
#pragma unroll
    for (int ci = 0; ci < 64; ++ci) {
        const float* q = xb + ci * 9216 + ph * 2 * 96 + pw * 2;
        xin[ci] = 0.25f * (q[0] + q[1] + q[96] + q[97]);
    }
    float alpha = a2[0];
    float* dst = refb2 + (size_t)b * 32 * 2304;
#pragma unroll
    for (int c = 0; c < 16; ++c) {
        int co = co0 + c;
        float s = b2[co];
#pragma unroll
        for (int ci = 0; ci < 64; ++ci) s += W2[co * 64 + ci] * xin[ci];
        dst[co * 2304 + p] = s >= 0.f ? s : alpha * s;
    }
}

// ---------------------------------------------------------------- per-batch builds

// xp[q][k=c*9+kh*3+kw] = match[c][qh+kh-1][qw+kw-1] (zero pad), fp16.
__global__ __launch_bounds__(256) void build_xp(const float* __restrict__ match,
                                                _Float16* __restrict__ xp) {
    int q = blockIdx.x * 4 + (threadIdx.x >> 6);
    int lane = threadIdx.x & 63;
    int qh = q / 96, qw = q % 96;
#pragma unroll
    for (int t = 0; t < 5; ++t) {
        int k = lane + t * 64;
        if (k < 288) {
            int c = k / 9, r = k % 9;
            int y = qh + r / 3 - 1, x = qw + r % 3 - 1;
            float v = (y >= 0 && y < 96 && x >= 0 && x < 96) ? match[c * 9216 + y * 96 + x] : 0.f;
            xp[(size_t)q * 288 + k] = (_Float16)v;
        }
    }
}

// wn[l][c*9+kh*3+kw] = 10 * patch / max(||patch||, 1e-4), fp16.  1 wave per l.
__global__ void build_wn(const float* __restrict__ ref, _Float16* __restrict__ wn) {
    int l = blockIdx.x;  // 2304
    int oh = l / 48, ow = l % 48;
    int lane = threadIdx.x;  // 64
    float vals[5];
    float ss = 0.f;
#pragma unroll
    for (int t = 0; t < 5; ++t) {
        int i = lane + t * 64;
        float v = 0.f;
        if (i < 288) {
            int c = i / 9, r = i % 9, kh = r / 3, kw = r % 3;
            int y = oh + kh - 1, x = ow + kw - 1;
            v = (y >= 0 && y < 48 && x >= 0 && x < 48) ? ref[c * 2304 + y * 48 + x] : 0.f;
        }
        vals[t] = v;
        ss += v * v;
    }
#pragma unroll
    for (int d = 32; d; d >>= 1) ss += __shfl_xor(ss, d);
    float norm = sqrtf(ss);
    norm = norm < 1e-4f ? 1e-4f : norm;
    float inv = 10.f / norm;  // fold SOFTMAX_SCALE here
#pragma unroll
    for (int t = 0; t < 5; ++t) {
        int i = lane + t * 64;
        if (i < 288) wn[(size_t)l * 288 + i] = (_Float16)(vals[t] * inv);
    }
}

// Wt[row=(o*36+i*6+j)][l=(lh*48+lw)] = embed[o][2lh+i-2][2lw+j-2] (zero pad), fp16
__global__ void build_Wt(const float* __restrict__ embed, _Float16* __restrict__ Wt) {
    int idx = blockIdx.x * 256 + threadIdx.x;
    if (idx >= 2304 * 2304) return;
    int row = idx / 2304, l = idx % 2304;
    int o = row / 36, rem = row % 36, i = rem / 6, j = rem % 6;
    int lh = l / 48, lw = l % 48;
    int y = 2 * lh + i - 2, x = 2 * lw + j - 2;
    float v = (y >= 0 && y < 96 && x >= 0 && x < 96) ? embed[o * 9216 + y * 96 + x] : 0.f;
    Wt[idx] = (_Float16)v;
}

// row softmax over l=2304 per q, fp16 logits in, fp16 normalized weights out
__global__ __launch_bounds__(256) void softmax_rows(const _Float16* __restrict__ S16,
                                                    _Float16* __restrict__ yi) {
    int q = blockIdx.x;
    const _Float16* row = S16 + (size_t)q * 2304;
    int tid = threadIdx.x;
    float v[9];
    float m = -1e30f;
#pragma unroll
    for (int t = 0; t < 9; ++t) {
        v[t] = (float)row[tid + t * 256];
        m = fmaxf(m, v[t]);
    }
    __shared__ float red[8];
#pragma unroll
    for (int d = 32; d; d >>= 1) m = fmaxf(m, __shfl_xor(m, d));
    if ((tid & 63) == 0) red[tid >> 6] = m;
    __syncthreads();
    m = fmaxf(fmaxf(red[0], red[1]), fmaxf(red[2], red[3]));
    float s = 0.f;
#pragma unroll
    for (int t = 0; t < 9; ++t) {
        v[t] = expf(v[t] - m);
        s += v[t];
    }
#pragma unroll
    for (int d = 32; d; d >>= 1) s += __shfl_xor(s, d);
    __syncthreads();
    if ((tid & 63) == 0) red[(tid >> 6) + 4] = s;
    __syncthreads();
    s = red[4] + red[5] + red[6] + red[7];
    float inv = 1.f / s;
    _Float16* orow = yi + (size_t)q * 2304;
#pragma unroll
    for (int t = 0; t < 9; ++t) orow[tid + t * 256] = (_Float16)(v[t] * inv);
}

// ---------------------------------------------------------------- MFMA GEMM (BK=32)
// C[M][N] = sum_k A[M][K] * B[N][K]  (K-contiguous fp16), fp32 accum.
// MODE 0: fp32 store.  MODE 1: fp16 store.  MODE 2: rows<64, (acc+bias[row])/6.
// Used for GEMM1 (K=288, fp16 out) and GEMM3 (K=576).
template <int MODE>
__global__ __launch_bounds__(256) void gemm16(const _Float16* __restrict__ A,
                                              const _Float16* __restrict__ B, int M, int N, int K,
                                              void* __restrict__ outv,
                                              const float* __restrict__ bias) {
    __shared__ _Float16 As[128 * 32];
    __shared__ _Float16 Bs[128 * 32];
    int tid = threadIdx.x;
    int wave = tid >> 6, lane = tid & 63;
    int wm = wave >> 1, wn_ = wave & 1;  // 2x2 wave grid, 64x64 per wave
    int quad = lane >> 4, mrow = lane & 15;
    int m0 = blockIdx.y * 128, n0 = blockIdx.x * 128;
    int lrow = lane >> 2, lslot = lane & 3;
    float4v acc[4][4] = {};

    for (int k0 = 0; k0 < K; k0 += 32) {
#pragma unroll
        for (int r = 0; r < 2; ++r) {
            int c = wave * 2 + r;  // 0..7 — 8 x 1KB chunks per matrix
            int row = c * 16 + lrow;
            int cc = lslot ^ ((row >> 1) & 3);
            const _Float16* ga = A + (size_t)(m0 + row) * K + k0 + cc * 8;
            const _Float16* gb = B + (size_t)(n0 + row) * K + k0 + cc * 8;
            __builtin_amdgcn_global_load_lds(
                (const __attribute__((address_space(1))) unsigned int*)ga,
                (__attribute__((address_space(3))) unsigned int*)&As[c * 512], 16, 0, 0);
            __builtin_amdgcn_global_load_lds(
                (const __attribute__((address_space(1))) unsigned int*)gb,
                (__attribute__((address_space(3))) unsigned int*)&Bs[c * 512], 16, 0, 0);
        }
        __syncthreads();
        half8 af[4], bf[4];
#pragma unroll
        for (int t = 0; t < 4; ++t) {
            int arow = wm * 64 + t * 16 + mrow;
            af[t] = *(const half8*)&As[arow * 32 + (quad ^ ((arow >> 1) & 3)) * 8];
            int brow = wn_ * 64 + t * 16 + mrow;
            bf[t] = *(const half8*)&Bs[brow * 32 + (quad ^ ((brow >> 1) & 3)) * 8];
        }
#pragma unroll
        for (int i = 0; i < 4; ++i)
#pragma unroll
            for (int j = 0; j < 4; ++j)
                acc[i][j] = __builtin_amdgcn_mfma_f32_16x16x32_f16(af[i], bf[j], acc[i][j], 0, 0, 0);
        __syncthreads();
    }

#pragma unroll
    for (int i = 0; i < 4; ++i)
#pragma unroll
        for (int j = 0; j < 4; ++j)
#pragma unroll
            for (int r = 0; r < 4; ++r) {
                int row = m0 + wm * 64 + i * 16 + quad * 4 + r;
                int col = n0 + wn_ * 64 + j * 16 + mrow;
                float v = acc[i][j][r];
                if (MODE == 0) {
                    ((float*)outv)[(size_t)row * N + col] = v;
                } else if (MODE == 1) {
                    ((_Float16*)outv)[(size_t)row * N + col] = (_Float16)v;
                } else {
                    if (row < 64)
                        ((float*)outv)[(size_t)row * N + col] = (v + bias[row]) * (1.f / 6.f);
                }
            }
}

// ---------------------------------------------------------------- MFMA GEMM (BK=64)
// Same contract, fp16 output, K % 64 == 0. 32 MFMA per barrier pair. LDS 2x16 KB.
// Rows are 128 B = 8 x 16B slots; phys slot = src ^ (row&7): 2 lanes/bank (free).
__global__ __launch_bounds__(256) void gemm16_bk64(const _Float16* __restrict__ A,
                                                   const _Float16* __restrict__ B,
                                                   int M, int N, int K,
                                                   _Float16* __restrict__ out) {
    __shared__ _Float16 As[128 * 64];
    __shared__ _Float16 Bs[128 * 64];
    int tid = threadIdx.x;
    int wave = tid >> 6, lane = tid & 63;
    int wm = wave >> 1, wn_ = wave & 1;  // 2x2 wave grid, 64x64 per wave
    int quad = lane >> 4, mrow = lane & 15;
    int m0 = blockIdx.y * 128, n0 = blockIdx.x * 128;
    int crow = lane >> 3, cslot = lane & 7;  // staging: 8 rows x 8 slots per 1KB chunk
    float4v acc[4][4] = {};

    for (int k0 = 0; k0 < K; k0 += 64) {
#pragma unroll
        for (int r = 0; r < 4; ++r) {
            int c = wave * 4 + r;        // 0..15
            int row = c * 8 + crow;      // 0..127
            int ss = cslot ^ (row & 7);
            const _Float16* ga = A + (size_t)(m0 + row) * K + k0 + ss * 8;
            const _Float16* gb = B + (size_t)(n0 + row) * K + k0 + ss * 8;
            __builtin_amdgcn_global_load_lds(
                (const __attribute__((address_space(1))) unsigned int*)ga,
                (__attribute__((address_space(3))) unsigned int*)&As[c * 512], 16, 0, 0);
            __builtin_amdgcn_global_load_lds(
                (const __attribute__((address_space(1))) unsigned int*)gb,
                (__attribute__((address_space(3))) unsigned int*)&Bs[c * 512], 16, 0, 0);
        }
        __syncthreads();
        half8 af[2][4], bf[2][4];
#pragma unroll
        for (int d = 0; d < 2; ++d)
#pragma unroll
            for (int t = 0; t < 4; ++t) {
                int ar = wm * 64 + t * 16 + mrow;
                af[d][t] = *(const half8*)&As[ar * 64 + (((d * 4 + quad) ^ (ar & 7)) * 8)];
                int br = wn_ * 64 + t * 16 + mrow;
                bf[d][t] = *(const half8*)&Bs[br * 64 + (((d * 4 + quad) ^ (br & 7)) * 8)];
            }
#pragma unroll
        for (int d = 0; d < 2; ++d)
#pragma unroll
            for (int i = 0; i < 4; ++i)
#pragma unroll
                for (int j = 0; j < 4; ++j)
                    acc[i][j] =
                        __builtin_amdgcn_mfma_f32_16x16x32_f16(af[d][i], bf[d][j], acc[i][j], 0, 0, 0);
        __syncthreads();
    }

#pragma unroll
    for (int i = 0; i < 4; ++i)
#pragma unroll
        for (int j = 0; j < 4; ++j)
#pragma unroll
            for (int r = 0; r < 4; ++r) {
                int row = m0 + wm * 64 + i * 16 + quad * 4 + r;
                int col = n0 + wn_ * 64 + j * 16 + mrow;
                out[(size_t)row * N + col] = (_Float16)acc[i][j][r];
            }
}

// ---------------------------------------------------------------- tail

// gather (inverse of tconv scatter): yth[o][Y][X] = sum_{i==Y%2, j==X%2 (mod 2)}
//   Z[(o*36+i*6+j)][h*96+w],  h=(Y+2-i)/2, w=(X+2-j)/2 in range. fp16 in/out.
__global__ void gather_yt(const _Float16* __restrict__ Z, _Float16* __restrict__ yth) {
    int idx = blockIdx.x * 256 + threadIdx.x;
    if (idx >= 64 * 192 * 192) return;
    int o = idx / 36864, r = idx % 36864, Y = r / 192, X = r % 192;
    float s = 0.f;
    for (int i = Y & 1; i < 6; i += 2) {
        int h2 = Y + 2 - i;
        if (h2 < 0) continue;
        int h = h2 >> 1;
        if (h >= 96) continue;
        for (int j = X & 1; j < 6; j += 2) {
            int w2 = X + 2 - j;
            if (w2 < 0) continue;
            int w = w2 >> 1;
            if (w >= 96) continue;
            s += (float)Z[(size_t)(o * 36 + i * 6 + j) * 9216 + h * 96 + w];
        }
    }
    yth[idx] = (_Float16)s;
}

// im2col for the down conv (3x3, stride 2, pad 1), wave per q, lane-contiguous k.
__global__ __launch_bounds__(256) void build_P(const _Float16* __restrict__ yth,
                                               _Float16* __restrict__ P) {
    int q = blockIdx.x * 4 + (threadIdx.x >> 6);
    int lane = threadIdx.x & 63;
    int y = q / 96, x = q % 96;
#pragma unroll
    for (int t = 0; t < 9; ++t) {
        int k = lane + t * 64;
        int o = k / 9, r = k % 9;
        int Y = 2 * y - 1 + r / 3, X = 2 * x - 1 + r % 3;
        _Float16 v = (_Float16)0.f;
        if (Y >= 0 && Y < 192 && X >= 0 && X < 192) v = yth[o * 36864 + Y * 192 + X];
        P[(size_t)q * 576 + k] = v;
    }
}

// Wdh[op][k] fp16, rows 64..127 zero-padded
__global__ void build_Wdh(const float* __restrict__ Wd, _Float16* __restrict__ Wdh) {
    int idx = blockIdx.x * 256 + threadIdx.x;
    if (idx >= 128 * 576) return;
    int op = idx / 576;
    Wdh[idx] = (_Float16)(op < 64 ? Wd[idx] : 0.f);
}

// ---------------------------------------------------------------- launch

extern "C" void kernel_launch(void* const* d_in, const int* in_sizes, int n_in,
                              void* d_out, int out_size, void* d_ws, size_t ws_size,
                              hipStream_t stream) {
    const float* x = (const float*)d_in[0];
    const float* W1 = (const float*)d_in[1];
    const float* b1 = (const float*)d_in[2];
    const float* a1 = (const float*)d_in[3];
    const float* W2 = (const float*)d_in[4];
    const float* b2 = (const float*)d_in[5];
    const float* a2 = (const float*)d_in[6];
    const float* Wa = (const float*)d_in[7];
    const float* ba = (const float*)d_in[8];
    const float* aa = (const float*)d_in[9];
    const float* Wd = (const float*)d_in[10];
    const float* bd = (const float*)d_in[11];
    float* out = (float*)d_out;

    char* ws = (char*)d_ws;
    char* sreg = ws;                 ws += 84934656;  // region: S16 fp16 logits, then Z fp16
    _Float16* yi = (_Float16*)ws;    ws += 42467328;  // [9216][2304] fp16 softmax; P aliases
    _Float16* Wt = (_Float16*)ws;    ws += 10616832;  // [2304][2304] fp16; yth aliases
    _Float16* xp = (_Float16*)ws;    ws += 5308416;   // [9216][288] fp16
    _Float16* wn = (_Float16*)ws;    ws += 1327104;   // [2304][288] fp16 (x10 folded)
    float* embed2 = (float*)ws;      ws += 4718592;   // [2][64][96][96]
    float* match2 = (float*)ws;      ws += 2359296;   // [2][32][96][96]
    float* refb2 = (float*)ws;       ws += 589824;    // [2][32][48][48]
    _Float16* Wdh = (_Float16*)ws;   ws += 147456;    // [128][576] fp16 (rows 64+ zero)
    // region aliases (writer runs strictly after the last read of the aliased data)
    _Float16* S16 = (_Float16*)sreg;  // [9216][2304] fp16 logits (42.5 MB)
    _Float16* Z = (_Float16*)sreg;    // [2304][9216] fp16 — after softmax consumed S16
    _Float16* P = yi;                 // [9216][576] fp16 — after GEMM2 consumed yi
    _Float16* yth = Wt;               // [64][192][192] fp16 — after GEMM2 consumed Wt

    build_Wdh<<<288, 256, 0, stream>>>(Wd, Wdh);
    // batched front: both images at once (tiny grids otherwise underfill 256 CUs)
    conv_embed_match<<<dim3(36, 6, 2), 256, 0, stream>>>(x, Wa, ba, aa, W1, b1, a1, embed2, match2);
    conv_ref_pooled<<<dim3(9, 2, 2), 256, 0, stream>>>(x, W2, b2, a2, refb2);

    for (int b = 0; b < 2; ++b) {
        float* outb = out + (size_t)b * 64 * 9216;
        const float* embed = embed2 + (size_t)b * 64 * 9216;
        const float* match = match2 + (size_t)b * 32 * 9216;
        const float* refb = refb2 + (size_t)b * 32 * 2304;

        build_xp<<<2304, 256, 0, stream>>>(match, xp);
        build_wn<<<2304, 64, 0, stream>>>(refb, wn);
        build_Wt<<<20736, 256, 0, stream>>>(embed, Wt);

        // GEMM1 (BK=32, fp16 out): S16[q][l] = <xp[q], wn[l]> (x10 folded into wn)
        gemm16<1><<<dim3(18, 72), 256, 0, stream>>>(xp, wn, 9216, 2304, 288, S16, nullptr);
        softmax_rows<<<9216, 256, 0, stream>>>(S16, yi);

        // GEMM2 (BK=64): Z[(oij)][q] = sum_l Wt[(oij)][l] * yi[q][l]  (fp16 store)
        gemm16_bk64<<<dim3(72, 18), 256, 0, stream>>>(Wt, yi, 2304, 9216, 2304, Z);

        gather_yt<<<9216, 256, 0, stream>>>(Z, yth);
        build_P<<<2304, 256, 0, stream>>>(yth, P);
        // GEMM3 (down conv): out[op][q] = (sum_k Wdh[op][k] P[q][k] + bd[op]) / 6
        gemm16<2><<<dim3(72, 1), 256, 0, stream>>>(Wdh, P, 128, 9216, 576, outb, bd);
    }
}